// Round 2
// baseline (1155.657 us; speedup 1.0000x reference)
//
#include <hip/hip_runtime.h>
#include <hip/hip_bf16.h>
#include <math.h>

#define BATCH 8
#define HH 1024
#define WW 1024

// ---------------------------------------------------------------------------
// dtype-flag helpers: flag==1 -> inputs are bf16, flag==0 -> f32.
// ---------------------------------------------------------------------------
__device__ __forceinline__ float ldf(const void* p, int i, int isb) {
    if (isb) return __bfloat162float(((const __hip_bfloat16*)p)[i]);
    return ((const float*)p)[i];
}

// Probe d_in[18] (fw1: 256x1024 random normal, never exactly zero).
// bf16 data: every u16 is a bf16 with exponent field in ~[90,128).
// f32 data: half the u16s are uniform mantissa bits -> ~57% pass rate.
__global__ __launch_bounds__(64) void detect_k(const unsigned short* __restrict__ p,
                                               int* __restrict__ flag) {
    __shared__ int cnt[64];
    int t = threadIdx.x;
    int c = 0;
    for (int i = t; i < 4096; i += 64) {
        unsigned e = (p[i] >> 7) & 0xFF;
        if (e >= 90 && e < 128) c++;
    }
    cnt[t] = c;
    __syncthreads();
    if (t == 0) {
        int s = 0;
        for (int i = 0; i < 64; ++i) s += cnt[i];
        *flag = (s > 3686) ? 1 : 0;  // >90% => bf16
    }
}

// ---------------------------------------------------------------------------
// conv0: input = concat(nearest_resize(lqs,256) [3ch], evs [15ch]) -> 18ch
//        w (8,18,3,3) stride2 pad1 + bias + relu -> [B,8,128,128]
// ---------------------------------------------------------------------------
__global__ __launch_bounds__(256) void conv0_k(const void* __restrict__ lqs,
                                               const void* __restrict__ evs,
                                               const void* __restrict__ w,
                                               const void* __restrict__ bias,
                                               const int* __restrict__ flag,
                                               float* __restrict__ out) {
    const int isb = *flag;
    const int OH = 128, OW = 128, OC = 8, IC = 18, IH = 256, IW = 256;
    int idx = blockIdx.x * blockDim.x + threadIdx.x;
    if (idx >= BATCH * OC * OH * OW) return;
    int ox = idx % OW;
    int oy = (idx / OW) % OH;
    int oc = (idx / (OW * OH)) % OC;
    int b = idx / (OW * OH * OC);
    float acc = ldf(bias, oc, isb);
    int iy0 = oy * 2 - 1, ix0 = ox * 2 - 1;
    for (int ic = 0; ic < IC; ++ic) {
        int wbase = (oc * IC + ic) * 9;
#pragma unroll
        for (int ky = 0; ky < 3; ++ky) {
            int iy = iy0 + ky;
            if (iy < 0 || iy >= IH) continue;
#pragma unroll
            for (int kx = 0; kx < 3; ++kx) {
                int ix = ix0 + kx;
                if (ix < 0 || ix >= IW) continue;
                float v;
                if (ic < 3) {
                    v = ldf(lqs, ((b * 3 + ic) * HH + iy * 4) * WW + ix * 4, isb);
                } else {
                    v = ldf(evs, ((b * 15 + (ic - 3)) * 256 + iy) * 256 + ix, isb);
                }
                acc = fmaf(ldf(w, wbase + ky * 3 + kx, isb), v, acc);
            }
        }
    }
    out[idx] = fmaxf(acc, 0.0f);
}

// ---------------------------------------------------------------------------
// generic 3x3 conv, pad=1; input is f32 ws buffer, weights/bias are d_in.
// ---------------------------------------------------------------------------
template <int IC, int OC, int IH, int IW, int STRIDE, bool RELU, bool HASB>
__global__ __launch_bounds__(256) void conv3x3_k(const float* __restrict__ in,
                                                 const void* __restrict__ w,
                                                 const void* __restrict__ bias,
                                                 const int* __restrict__ flag,
                                                 float* __restrict__ out) {
    const int isb = *flag;
    constexpr int OH = (IH + 2 - 3) / STRIDE + 1;
    constexpr int OW = (IW + 2 - 3) / STRIDE + 1;
    int idx = blockIdx.x * blockDim.x + threadIdx.x;
    if (idx >= BATCH * OC * OH * OW) return;
    int ox = idx % OW;
    int oy = (idx / OW) % OH;
    int oc = (idx / (OW * OH)) % OC;
    int b = idx / (OW * OH * OC);
    float acc = HASB ? ldf(bias, oc, isb) : 0.0f;
    const float* ip = in + b * IC * IH * IW;
    int iy0 = oy * STRIDE - 1, ix0 = ox * STRIDE - 1;
    for (int ic = 0; ic < IC; ++ic) {
        const float* ipc = ip + ic * IH * IW;
        int wbase = (oc * IC + ic) * 9;
#pragma unroll
        for (int ky = 0; ky < 3; ++ky) {
            int iy = iy0 + ky;
            if (iy < 0 || iy >= IH) continue;
#pragma unroll
            for (int kx = 0; kx < 3; ++kx) {
                int ix = ix0 + kx;
                if (ix < 0 || ix >= IW) continue;
                acc = fmaf(ldf(w, wbase + ky * 3 + kx, isb), ipc[iy * IW + ix], acc);
            }
        }
    }
    if (RELU) acc = fmaxf(acc, 0.0f);
    out[idx] = acc;
}

// ---------------------------------------------------------------------------
// fused FC stack: [B,1024] -> 256 relu -> 128 relu -> 64. One block per batch.
// ---------------------------------------------------------------------------
__global__ __launch_bounds__(256) void fc_k(const float* __restrict__ xin_g,
                                            const void* __restrict__ fw1, const void* __restrict__ fb1,
                                            const void* __restrict__ fw2, const void* __restrict__ fb2,
                                            const void* __restrict__ fw3, const void* __restrict__ fb3,
                                            const int* __restrict__ flag,
                                            float* __restrict__ xg_out) {
    const int isb = *flag;
    __shared__ float xin[1024];
    __shared__ float h1[256];
    __shared__ float h2[128];
    int b = blockIdx.x, t = threadIdx.x;
    for (int i = t; i < 1024; i += 256) xin[i] = xin_g[b * 1024 + i];
    __syncthreads();
    {
        float acc = ldf(fb1, t, isb);
        int wb = t * 1024;
#pragma unroll 8
        for (int k = 0; k < 1024; ++k) acc = fmaf(ldf(fw1, wb + k, isb), xin[k], acc);
        h1[t] = fmaxf(acc, 0.0f);
    }
    __syncthreads();
    if (t < 128) {
        float acc = ldf(fb2, t, isb);
        int wb = t * 256;
#pragma unroll 8
        for (int k = 0; k < 256; ++k) acc = fmaf(ldf(fw2, wb + k, isb), h1[k], acc);
        h2[t] = fmaxf(acc, 0.0f);
    }
    __syncthreads();
    if (t < 64) {
        float acc = ldf(fb3, t, isb);
        int wb = t * 128;
#pragma unroll 8
        for (int k = 0; k < 128; ++k) acc = fmaf(ldf(fw3, wb + k, isb), h2[k], acc);
        xg_out[b * 64 + t] = acc;
    }
}

// ---------------------------------------------------------------------------
// fused = relu(xg[b,c] + xl[b,c,y,x]); bg[b,d,y,x] = sum_c fuw[d,c]*fused + fub[d]
// ---------------------------------------------------------------------------
__global__ __launch_bounds__(256) void fuse_k(const float* __restrict__ xg,
                                              const float* __restrict__ xl,
                                              const void* __restrict__ fuw,
                                              const void* __restrict__ fub,
                                              const int* __restrict__ flag,
                                              float* __restrict__ bg) {
    const int isb = *flag;
    int idx = blockIdx.x * blockDim.x + threadIdx.x;  // B*8*256
    if (idx >= BATCH * 8 * 256) return;
    int px = idx % 256;
    int d = (idx / 256) % 8;
    int b = idx / 2048;
    float acc = ldf(fub, d, isb);
    for (int c = 0; c < 64; ++c) {
        float f = xg[b * 64 + c] + xl[(b * 64 + c) * 256 + px];
        f = fmaxf(f, 0.0f);
        acc = fmaf(ldf(fuw, d * 64 + c, isb), f, acc);
    }
    bg[idx] = acc;
}

// ---------------------------------------------------------------------------
// Big fused kernel: 17x17 separable gaussian (reflect pad) -> 1x1 convs ->
// guide -> trilinear slice of bilateral grid -> out (bf16 or f32 per flag).
// Tile: 64(x) x 16(y) outputs per block, 256 threads.
// ---------------------------------------------------------------------------
__global__ __launch_bounds__(256) void guide_slice_k(const void* __restrict__ lqs,
                                                     const float* __restrict__ bg,
                                                     const void* __restrict__ gw1,
                                                     const void* __restrict__ gb1,
                                                     const void* __restrict__ gw2,
                                                     const void* __restrict__ gb2,
                                                     const int* __restrict__ flag,
                                                     void* __restrict__ out) {
    const int isb = *flag;
    constexpr int TW = 64, TH = 16;
    __shared__ float sBH[3][TH + 16][TW];  // horizontally-blurred rows (+8 halo)
    __shared__ float sBG[2048];            // bilateral grid for this batch [8][16][16]
    __shared__ float sW1[48], sB1[16], sW2[16], sB2v[1];

    int bx = blockIdx.x % (WW / TW);
    int by = (blockIdx.x / (WW / TW)) % (HH / TH);
    int b = blockIdx.x / ((WW / TW) * (HH / TH));
    int x0 = bx * TW, y0 = by * TH;
    int t = threadIdx.x;

    float gv[17];
    {
        float gs = 0.0f;
#pragma unroll
        for (int i = 0; i < 17; ++i) {
            float d = (float)i - 8.0f;
            gv[i] = expf(-(d * d) * 0.125f);
            gs += gv[i];
        }
        float inv = 1.0f / gs;
#pragma unroll
        for (int i = 0; i < 17; ++i) gv[i] *= inv;
    }

    for (int i = t; i < 2048; i += 256) sBG[i] = bg[b * 2048 + i];
    if (t < 48) sW1[t] = ldf(gw1, t, isb);
    if (t < 16) sB1[t] = ldf(gb1, t, isb);
    if (t < 16) sW2[t] = ldf(gw2, t, isb);
    if (t == 0) sB2v[0] = ldf(gb2, 0, isb);

    // stage 1: horizontal blur into LDS (reflect padding against full image)
    for (int e = t; e < 3 * (TH + 16) * TW; e += 256) {
        int tx = e % TW;
        int ry = (e / TW) % (TH + 16);
        int c = e / (TW * (TH + 16));
        int gy = y0 + ry - 8;
        gy = gy < 0 ? -gy : (gy > HH - 1 ? 2 * (HH - 1) - gy : gy);
        int rowb = ((b * 3 + c) * HH + gy) * WW;
        float acc = 0.0f;
#pragma unroll
        for (int i = 0; i < 17; ++i) {
            int gx = x0 + tx - 8 + i;
            gx = gx < 0 ? -gx : (gx > WW - 1 ? 2 * (WW - 1) - gx : gx);
            acc = fmaf(gv[i], ldf(lqs, rowb + gx, isb), acc);
        }
        sBH[c][ry][tx] = acc;
    }
    __syncthreads();

    // stage 2: vertical blur, guide, trilinear slice
#pragma unroll
    for (int k = 0; k < 4; ++k) {
        int px = t + k * 256;
        int ox = px % TW, oy = px / TW;
        float bc[3];
#pragma unroll
        for (int c = 0; c < 3; ++c) {
            float acc = 0.0f;
#pragma unroll
            for (int i = 0; i < 17; ++i) acc = fmaf(gv[i], sBH[c][oy + i][ox], acc);
            bc[c] = acc;
        }
        float s = sB2v[0];
#pragma unroll
        for (int c = 0; c < 16; ++c) {
            float g1 = fmaf(sW1[c * 3 + 0], bc[0],
                        fmaf(sW1[c * 3 + 1], bc[1],
                         fmaf(sW1[c * 3 + 2], bc[2], sB1[c])));
            g1 = fmaxf(g1, 0.0f);
            s = fmaf(sW2[c], g1, s);
        }
        float sig = 1.0f / (1.0f + expf(-s));
        float guide = sig * 2.0f - 0.5f;

        int X = x0 + ox, Y = y0 + oy;
        float fx = fminf(fmaxf((X + 0.5f) * (1.0f / 64.0f) + 3.5f, 0.0f), 15.0f);
        float fy = fminf(fmaxf((Y + 0.5f) * (1.0f / 64.0f) + 3.5f, 0.0f), 15.0f);
        float fz = fminf(fmaxf(guide * 4.0f + 3.5f, 0.0f), 7.0f);
        float xf = floorf(fx), yf = floorf(fy), zf = floorf(fz);
        int xi = (int)xf, yi = (int)yf, zi = (int)zf;
        float ax = fx - xf, ay = fy - yf, az = fz - zf;
        int xi1 = min(xi + 1, 15), yi1 = min(yi + 1, 15), zi1 = min(zi + 1, 7);

        float v000 = sBG[(zi * 16 + yi) * 16 + xi];
        float v001 = sBG[(zi * 16 + yi) * 16 + xi1];
        float v010 = sBG[(zi * 16 + yi1) * 16 + xi];
        float v011 = sBG[(zi * 16 + yi1) * 16 + xi1];
        float v100 = sBG[(zi1 * 16 + yi) * 16 + xi];
        float v101 = sBG[(zi1 * 16 + yi) * 16 + xi1];
        float v110 = sBG[(zi1 * 16 + yi1) * 16 + xi];
        float v111 = sBG[(zi1 * 16 + yi1) * 16 + xi1];

        float wz0 = 1.0f - az, wz1 = az;
        float wy0 = 1.0f - ay, wy1 = ay;
        float wx0 = 1.0f - ax, wx1 = ax;
        float val = v000 * wz0 * wy0 * wx0 + v001 * wz0 * wy0 * wx1 +
                    v010 * wz0 * wy1 * wx0 + v011 * wz0 * wy1 * wx1 +
                    v100 * wz1 * wy0 * wx0 + v101 * wz1 * wy0 * wx1 +
                    v110 * wz1 * wy1 * wx0 + v111 * wz1 * wy1 * wx1;

        int o = b * HH * WW + Y * WW + X;
        if (isb) ((__hip_bfloat16*)out)[o] = __float2bfloat16(val);
        else ((float*)out)[o] = val;
    }
}

// ---------------------------------------------------------------------------
extern "C" void kernel_launch(void* const* d_in, const int* in_sizes, int n_in,
                              void* d_out, int out_size, void* d_ws, size_t ws_size,
                              hipStream_t stream) {
    const void* lqs = d_in[0];
    const void* evs = d_in[1];
    const void* gw1 = d_in[2];
    const void* gb1 = d_in[3];
    const void* gw2 = d_in[4];
    const void* gb2 = d_in[5];
    const void* sw0 = d_in[6];
    const void* sb0 = d_in[7];
    const void* sw1 = d_in[8];
    const void* sb1 = d_in[9];
    const void* sw2 = d_in[10];
    const void* sb2 = d_in[11];
    const void* sw3 = d_in[12];
    const void* sb3 = d_in[13];
    const void* cw0 = d_in[14];
    const void* cb0 = d_in[15];
    const void* cw1 = d_in[16];
    const void* cb1 = d_in[17];
    const void* fw1 = d_in[18];
    const void* fb1 = d_in[19];
    const void* fw2 = d_in[20];
    const void* fb2 = d_in[21];
    const void* fw3 = d_in[22];
    const void* fb3 = d_in[23];
    const void* lw1 = d_in[24];
    const void* lb1 = d_in[25];
    const void* lw2 = d_in[26];
    const void* fuw = d_in[27];
    const void* fub = d_in[28];

    float* ws = (float*)d_ws;
    float* o0 = ws;                    // [8,8,128,128]   1048576
    float* o1 = o0 + 1048576;          // [8,16,64,64]     524288
    float* o2 = o1 + 524288;           // [8,32,32,32]     262144
    float* o3 = o2 + 262144;           // [8,64,16,16]     131072
    float* xl1 = o3 + 131072;          // [8,64,16,16]     131072
    float* xl2 = xl1 + 131072;         // [8,64,16,16]     131072
    float* xg0 = xl2 + 131072;         // [8,64,8,8]        32768
    float* xg1 = xg0 + 32768;          // [8,64,4,4]         8192
    float* xgv = xg1 + 8192;           // [8,64]              512
    float* bg = xgv + 512;             // [8,8,16,16]       16384
    int* flag = (int*)(bg + 16384);

    detect_k<<<1, 64, 0, stream>>>((const unsigned short*)fw1, flag);
    // lowres stream
    conv0_k<<<(BATCH * 8 * 128 * 128 + 255) / 256, 256, 0, stream>>>(lqs, evs, sw0, sb0, flag, o0);
    conv3x3_k<8, 16, 128, 128, 2, true, true><<<(BATCH * 16 * 64 * 64 + 255) / 256, 256, 0, stream>>>(o0, sw1, sb1, flag, o1);
    conv3x3_k<16, 32, 64, 64, 2, true, true><<<(BATCH * 32 * 32 * 32 + 255) / 256, 256, 0, stream>>>(o1, sw2, sb2, flag, o2);
    conv3x3_k<32, 64, 32, 32, 2, true, true><<<(BATCH * 64 * 16 * 16 + 255) / 256, 256, 0, stream>>>(o2, sw3, sb3, flag, o3);
    // local path
    conv3x3_k<64, 64, 16, 16, 1, true, true><<<(BATCH * 64 * 16 * 16 + 255) / 256, 256, 0, stream>>>(o3, lw1, lb1, flag, xl1);
    conv3x3_k<64, 64, 16, 16, 1, false, false><<<(BATCH * 64 * 16 * 16 + 255) / 256, 256, 0, stream>>>(xl1, lw2, nullptr, flag, xl2);
    // global path
    conv3x3_k<64, 64, 16, 16, 2, true, true><<<(BATCH * 64 * 8 * 8 + 255) / 256, 256, 0, stream>>>(o3, cw0, cb0, flag, xg0);
    conv3x3_k<64, 64, 8, 8, 2, true, true><<<(BATCH * 64 * 4 * 4 + 255) / 256, 256, 0, stream>>>(xg0, cw1, cb1, flag, xg1);
    fc_k<<<BATCH, 256, 0, stream>>>(xg1, fw1, fb1, fw2, fb2, fw3, fb3, flag, xgv);
    fuse_k<<<(BATCH * 8 * 256 + 255) / 256, 256, 0, stream>>>(xgv, xl2, fuw, fub, flag, bg);
    // highres guide + slice
    guide_slice_k<<<BATCH * (HH / 16) * (WW / 64), 256, 0, stream>>>(lqs, bg, gw1, gb1, gw2, gb2, flag, d_out);
}

// Round 4
// 717.380 us; speedup vs baseline: 1.6109x; 1.6109x over previous
//
#include <hip/hip_runtime.h>
#include <hip/hip_bf16.h>
#include <math.h>

#define BATCH 8
#define HH 1024
#define WW 1024

__device__ __forceinline__ int reflect1024(int i) {
    i = i < 0 ? -i : i;
    return i > 1023 ? 2046 - i : i;
}

// ---------------------------------------------------------------------------
// conv0: input = concat(nearest_resize(lqs,256) [3ch], evs [15ch]) -> 18ch
//        w (8,18,3,3) stride2 pad1 + bias + relu -> [B,8,128,128]
// One block per 256 outputs of a single (b,oc) plane; weights in LDS.
// Valid-range: iy,ix in [-1,255]; only <0 needs masking.
// ---------------------------------------------------------------------------
__global__ __launch_bounds__(256) void conv0_k(const float* __restrict__ lqs,
                                               const float* __restrict__ evs,
                                               const float* __restrict__ w,
                                               const float* __restrict__ bias,
                                               float* __restrict__ out) {
    __shared__ float sw[162];
    __shared__ float sb;
    int t = threadIdx.x;
    int pid = blockIdx.x >> 6;  // 64 blocks per (b,oc) plane (128*128/256)
    int oc = pid & 7, b = pid >> 3;
    if (t < 162) sw[t] = w[oc * 162 + t];
    if (t == 0) sb = bias[oc];
    __syncthreads();
    int p = ((blockIdx.x & 63) << 8) | t;
    int ox = p & 127, oy = p >> 7;
    int iy0 = oy * 2 - 1, ix0 = ox * 2 - 1;
    float acc = sb;
    for (int ic = 0; ic < 3; ++ic) {
        const float* ipc = lqs + (size_t)(b * 3 + ic) * HH * WW;
        const float* wp = sw + ic * 9;
#pragma unroll
        for (int ky = 0; ky < 3; ++ky) {
            int iy = iy0 + ky;
            if (iy < 0) continue;
            const float* row = ipc + (size_t)iy * 4 * WW;
#pragma unroll
            for (int kx = 0; kx < 3; ++kx) {
                int ix = ix0 + kx;
                if (ix < 0) continue;
                acc = fmaf(wp[ky * 3 + kx], row[ix * 4], acc);
            }
        }
    }
    for (int ic = 0; ic < 15; ++ic) {
        const float* ipc = evs + (size_t)(b * 15 + ic) * 65536;
        const float* wp = sw + (ic + 3) * 9;
#pragma unroll
        for (int ky = 0; ky < 3; ++ky) {
            int iy = iy0 + ky;
            if (iy < 0) continue;
            const float* row = ipc + iy * 256;
#pragma unroll
            for (int kx = 0; kx < 3; ++kx) {
                int ix = ix0 + kx;
                if (ix < 0) continue;
                acc = fmaf(wp[ky * 3 + kx], row[ix], acc);
            }
        }
    }
    out[pid * 16384 + p] = fmaxf(acc, 0.0f);
}

// ---------------------------------------------------------------------------
// planar 3x3 conv: each block = 256 outputs of one (b,oc) plane, weights in
// LDS. Requires OH*OW % 256 == 0.
// ---------------------------------------------------------------------------
template <int IC, int OC, int IH, int IW, int STRIDE, bool RELU, bool HASB>
__global__ __launch_bounds__(256) void conv3x3_k(const float* __restrict__ in,
                                                 const float* __restrict__ w,
                                                 const float* __restrict__ bias,
                                                 float* __restrict__ out) {
    constexpr int OH = (IH + 2 - 3) / STRIDE + 1;
    constexpr int OW = (IW + 2 - 3) / STRIDE + 1;
    constexpr int BPP = (OH * OW) / 256;
    __shared__ float sw[IC * 9];
    __shared__ float sb;
    int t = threadIdx.x;
    int pid = blockIdx.x / BPP;
    int oc = pid % OC, b = pid / OC;
    for (int i = t; i < IC * 9; i += 256) sw[i] = w[oc * IC * 9 + i];
    if (t == 0) sb = HASB ? bias[oc] : 0.0f;
    __syncthreads();
    int p = (blockIdx.x % BPP) * 256 + t;
    int ox = p % OW, oy = p / OW;
    int iy0 = oy * STRIDE - 1, ix0 = ox * STRIDE - 1;
    float acc = sb;
    const float* ip = in + (size_t)b * IC * IH * IW;
    for (int ic = 0; ic < IC; ++ic) {
        const float* ipc = ip + ic * IH * IW;
        const float* wp = sw + ic * 9;
#pragma unroll
        for (int ky = 0; ky < 3; ++ky) {
            int iy = iy0 + ky;
            if (iy < 0 || iy >= IH) continue;
#pragma unroll
            for (int kx = 0; kx < 3; ++kx) {
                int ix = ix0 + kx;
                if (ix < 0 || ix >= IW) continue;
                acc = fmaf(wp[ky * 3 + kx], ipc[iy * IW + ix], acc);
            }
        }
    }
    if (RELU) acc = fmaxf(acc, 0.0f);
    out[pid * OH * OW + p] = acc;
}

// ---------------------------------------------------------------------------
// small conv (output plane < 256 px): one thread per output, weights global.
// ---------------------------------------------------------------------------
template <int IC, int OC, int IH, int IW, int STRIDE>
__global__ __launch_bounds__(256) void conv3x3_small_k(const float* __restrict__ in,
                                                       const float* __restrict__ w,
                                                       const float* __restrict__ bias,
                                                       float* __restrict__ out) {
    constexpr int OH = (IH + 2 - 3) / STRIDE + 1;
    constexpr int OW = (IW + 2 - 3) / STRIDE + 1;
    int idx = blockIdx.x * blockDim.x + threadIdx.x;
    if (idx >= BATCH * OC * OH * OW) return;
    int ox = idx % OW;
    int oy = (idx / OW) % OH;
    int oc = (idx / (OW * OH)) % OC;
    int b = idx / (OW * OH * OC);
    float acc = bias[oc];
    const float* ip = in + (size_t)b * IC * IH * IW;
    int iy0 = oy * STRIDE - 1, ix0 = ox * STRIDE - 1;
    for (int ic = 0; ic < IC; ++ic) {
        const float* ipc = ip + ic * IH * IW;
        const float* wpc = w + (oc * IC + ic) * 9;
#pragma unroll
        for (int ky = 0; ky < 3; ++ky) {
            int iy = iy0 + ky;
            if (iy < 0 || iy >= IH) continue;
#pragma unroll
            for (int kx = 0; kx < 3; ++kx) {
                int ix = ix0 + kx;
                if (ix < 0 || ix >= IW) continue;
                acc = fmaf(wpc[ky * 3 + kx], ipc[iy * IW + ix], acc);
            }
        }
    }
    out[idx] = fmaxf(acc, 0.0f);
}

// ---------------------------------------------------------------------------
// fused FC stack: [B,1024] -> 256 relu -> 128 relu -> 64. One block per batch.
// ---------------------------------------------------------------------------
__global__ __launch_bounds__(256) void fc_k(const float* __restrict__ xin_g,
                                            const float* __restrict__ fw1, const float* __restrict__ fb1,
                                            const float* __restrict__ fw2, const float* __restrict__ fb2,
                                            const float* __restrict__ fw3, const float* __restrict__ fb3,
                                            float* __restrict__ xg_out) {
    __shared__ float xin[1024];
    __shared__ float h1[256];
    __shared__ float h2[128];
    int b = blockIdx.x, t = threadIdx.x;
    for (int i = t; i < 1024; i += 256) xin[i] = xin_g[b * 1024 + i];
    __syncthreads();
    {
        float acc = fb1[t];
        const float* wr = fw1 + t * 1024;
#pragma unroll 8
        for (int k = 0; k < 1024; ++k) acc = fmaf(wr[k], xin[k], acc);
        h1[t] = fmaxf(acc, 0.0f);
    }
    __syncthreads();
    if (t < 128) {
        float acc = fb2[t];
        const float* wr = fw2 + t * 256;
#pragma unroll 8
        for (int k = 0; k < 256; ++k) acc = fmaf(wr[k], h1[k], acc);
        h2[t] = fmaxf(acc, 0.0f);
    }
    __syncthreads();
    if (t < 64) {
        float acc = fb3[t];
        const float* wr = fw3 + t * 128;
#pragma unroll 8
        for (int k = 0; k < 128; ++k) acc = fmaf(wr[k], h2[k], acc);
        xg_out[b * 64 + t] = acc;
    }
}

// ---------------------------------------------------------------------------
// fused = relu(xg[b,c] + xl[b,c,y,x]); bg[b,d,y,x] = sum_c fuw[d,c]*fused+fub
// ---------------------------------------------------------------------------
__global__ __launch_bounds__(256) void fuse_k(const float* __restrict__ xg,
                                              const float* __restrict__ xl,
                                              const float* __restrict__ fuw,
                                              const float* __restrict__ fub,
                                              float* __restrict__ bg) {
    int idx = blockIdx.x * blockDim.x + threadIdx.x;  // B*8*256
    if (idx >= BATCH * 8 * 256) return;
    int px = idx % 256;
    int d = (idx / 256) % 8;
    int b = idx / 2048;
    float acc = fub[d];
    for (int c = 0; c < 64; ++c) {
        float f = xg[b * 64 + c] + xl[(b * 64 + c) * 256 + px];
        f = fmaxf(f, 0.0f);
        acc = fmaf(fuw[d * 64 + c], f, acc);
    }
    bg[idx] = acc;
}

// ---------------------------------------------------------------------------
// guide+slice v2: vertical-first separable blur with sliding register
// windows, LDS 81-stride padding, per-px guide MLP + trilinear grid slice.
// Tile 64(x) x 32(y), 256 threads.
// ---------------------------------------------------------------------------
__global__ __launch_bounds__(256) void guide_slice_k(const float* __restrict__ lqs,
                                                     const float* __restrict__ bgp,
                                                     const float* __restrict__ gw1,
                                                     const float* __restrict__ gb1,
                                                     const float* __restrict__ gw2,
                                                     const float* __restrict__ gb2,
                                                     float* __restrict__ out) {
    constexpr int TW = 64, TH = 32;
    __shared__ float sBH[3][TH][81];  // vertically-blurred, 80 cols used (+1 pad)
    __shared__ float sBG[2048];       // bilateral grid [8][16][16]
    __shared__ float sW1[48], sB1[16], sW2[16], sB2v[1];

    int t = threadIdx.x;
    int bx = blockIdx.x & 15;         // WW/TW
    int by = (blockIdx.x >> 4) & 31;  // HH/TH
    int b = blockIdx.x >> 9;
    int x0 = bx * TW, y0 = by * TH;

    // gaussian weights (sigma=2, 17 taps), same formula as reference
    float gv[17];
    {
        float gs = 0.0f;
#pragma unroll
        for (int i = 0; i < 17; ++i) {
            float d = (float)i - 8.0f;
            gv[i] = expf(-(d * d) * 0.125f);
            gs += gv[i];
        }
        float inv = 1.0f / gs;
#pragma unroll
        for (int i = 0; i < 17; ++i) gv[i] *= inv;
    }

    for (int i = t; i < 2048; i += 256) sBG[i] = bgp[b * 2048 + i];
    if (t < 48) sW1[t] = gw1[t];
    if (t < 16) { sB1[t] = gb1[t]; sW2[t] = gw2[t]; }
    if (t == 0) sB2v[0] = gb2[0];

    // ---- stage 1: vertical blur, sliding window down each column ----
    // 240 threads = 3ch x 80 cols (x halo 8 each side); rows y0-8 .. y0+39.
    if (t < 240) {
        int c = t / 80, xo = t % 80;
        int gx = reflect1024(x0 + xo - 8);
        const float* colp = lqs + (size_t)(b * 3 + c) * HH * WW + gx;
        float win[17];
#pragma unroll
        for (int i = 0; i < 16; ++i)
            win[i] = colp[(size_t)reflect1024(y0 - 8 + i) * WW];
#pragma unroll
        for (int j = 0; j < TH; ++j) {
            win[(16 + j) % 17] = colp[(size_t)reflect1024(y0 + 8 + j) * WW];
            float acc = 0.0f;
#pragma unroll
            for (int i = 0; i < 17; ++i) acc = fmaf(gv[i], win[(j + i) % 17], acc);
            sBH[c][j][xo] = acc;
        }
    }
    __syncthreads();

    // ---- stage 2: horizontal blur (sliding window), guide MLP, slice ----
    int yy = t >> 3, xs = (t & 7) * 8;  // 32 rows x 8 col-runs of 8
    int Y = y0 + yy;
    float fy = fminf(fmaxf((Y + 0.5f) * (1.0f / 64.0f) + 3.5f, 0.0f), 15.0f);
    float yf = floorf(fy);
    int yi = (int)yf;
    float ay = fy - yf;
    int yi1 = min(yi + 1, 15);

    float bcv[3][8];
#pragma unroll
    for (int c = 0; c < 3; ++c) {
        float win[17];
#pragma unroll
        for (int i = 0; i < 16; ++i) win[i] = sBH[c][yy][xs + i];
#pragma unroll
        for (int j = 0; j < 8; ++j) {
            win[(16 + j) % 17] = sBH[c][yy][xs + 16 + j];
            float acc = 0.0f;
#pragma unroll
            for (int i = 0; i < 17; ++i) acc = fmaf(gv[i], win[(j + i) % 17], acc);
            bcv[c][j] = acc;
        }
    }

    float val[8];
#pragma unroll
    for (int j = 0; j < 8; ++j) {
        float b0 = bcv[0][j], b1 = bcv[1][j], b2 = bcv[2][j];
        float s = sB2v[0];
#pragma unroll
        for (int c = 0; c < 16; ++c) {
            float g1 = fmaf(sW1[c * 3 + 0], b0,
                       fmaf(sW1[c * 3 + 1], b1,
                       fmaf(sW1[c * 3 + 2], b2, sB1[c])));
            s = fmaf(sW2[c], fmaxf(g1, 0.0f), s);
        }
        float sig = 1.0f / (1.0f + expf(-s));
        float guide = sig * 2.0f - 0.5f;

        int X = x0 + xs + j;
        float fx = fminf(fmaxf((X + 0.5f) * (1.0f / 64.0f) + 3.5f, 0.0f), 15.0f);
        float fz = fminf(fmaxf(fmaf(guide, 4.0f, 3.5f), 0.0f), 7.0f);
        float xf = floorf(fx), zf = floorf(fz);
        int xi = (int)xf, zi = (int)zf;
        float ax = fx - xf, az = fz - zf;
        int xi1 = min(xi + 1, 15), zi1 = min(zi + 1, 7);

        const float* g0 = sBG + zi * 256;
        const float* g1p = sBG + zi1 * 256;
        int i00 = yi * 16 + xi, i01 = yi * 16 + xi1;
        int i10 = yi1 * 16 + xi, i11 = yi1 * 16 + xi1;
        float c00 = g0[i00] + az * (g1p[i00] - g0[i00]);
        float c01 = g0[i01] + az * (g1p[i01] - g0[i01]);
        float c10 = g0[i10] + az * (g1p[i10] - g0[i10]);
        float c11 = g0[i11] + az * (g1p[i11] - g0[i11]);
        float c0 = c00 + ay * (c10 - c00);
        float c1 = c01 + ay * (c11 - c01);
        val[j] = c0 + ax * (c1 - c0);
    }
    float4* op = (float4*)(out + (size_t)b * HH * WW + (size_t)Y * WW + x0 + xs);
    op[0] = make_float4(val[0], val[1], val[2], val[3]);
    op[1] = make_float4(val[4], val[5], val[6], val[7]);
}

// ---------------------------------------------------------------------------
extern "C" void kernel_launch(void* const* d_in, const int* in_sizes, int n_in,
                              void* d_out, int out_size, void* d_ws, size_t ws_size,
                              hipStream_t stream) {
    const float* lqs = (const float*)d_in[0];
    const float* evs = (const float*)d_in[1];
    const float* gw1 = (const float*)d_in[2];
    const float* gb1 = (const float*)d_in[3];
    const float* gw2 = (const float*)d_in[4];
    const float* gb2 = (const float*)d_in[5];
    const float* sw0 = (const float*)d_in[6];
    const float* sb0 = (const float*)d_in[7];
    const float* sw1 = (const float*)d_in[8];
    const float* sb1 = (const float*)d_in[9];
    const float* sw2 = (const float*)d_in[10];
    const float* sb2 = (const float*)d_in[11];
    const float* sw3 = (const float*)d_in[12];
    const float* sb3 = (const float*)d_in[13];
    const float* cw0 = (const float*)d_in[14];
    const float* cb0 = (const float*)d_in[15];
    const float* cw1 = (const float*)d_in[16];
    const float* cb1 = (const float*)d_in[17];
    const float* fw1 = (const float*)d_in[18];
    const float* fb1 = (const float*)d_in[19];
    const float* fw2 = (const float*)d_in[20];
    const float* fb2 = (const float*)d_in[21];
    const float* fw3 = (const float*)d_in[22];
    const float* fb3 = (const float*)d_in[23];
    const float* lw1 = (const float*)d_in[24];
    const float* lb1 = (const float*)d_in[25];
    const float* lw2 = (const float*)d_in[26];
    const float* fuw = (const float*)d_in[27];
    const float* fub = (const float*)d_in[28];
    float* out = (float*)d_out;

    float* ws = (float*)d_ws;
    float* o0 = ws;             // [8,8,128,128]   1048576
    float* o1 = o0 + 1048576;   // [8,16,64,64]     524288
    float* o2 = o1 + 524288;    // [8,32,32,32]     262144
    float* o3 = o2 + 262144;    // [8,64,16,16]     131072
    float* xl1 = o3 + 131072;   // [8,64,16,16]     131072
    float* xl2 = xl1 + 131072;  // [8,64,16,16]     131072
    float* xg0 = xl2 + 131072;  // [8,64,8,8]        32768
    float* xg1 = xg0 + 32768;   // [8,64,4,4]         8192
    float* xgv = xg1 + 8192;    // [8,64]              512
    float* bg = xgv + 512;      // [8,8,16,16]       16384

    // lowres stream
    conv0_k<<<4096, 256, 0, stream>>>(lqs, evs, sw0, sb0, o0);
    conv3x3_k<8, 16, 128, 128, 2, true, true><<<2048, 256, 0, stream>>>(o0, sw1, sb1, o1);
    conv3x3_k<16, 32, 64, 64, 2, true, true><<<1024, 256, 0, stream>>>(o1, sw2, sb2, o2);
    conv3x3_k<32, 64, 32, 32, 2, true, true><<<512, 256, 0, stream>>>(o2, sw3, sb3, o3);
    // local path
    conv3x3_k<64, 64, 16, 16, 1, true, true><<<512, 256, 0, stream>>>(o3, lw1, lb1, xl1);
    conv3x3_k<64, 64, 16, 16, 1, false, false><<<512, 256, 0, stream>>>(xl1, lw2, nullptr, xl2);
    // global path
    conv3x3_small_k<64, 64, 16, 16, 2><<<128, 256, 0, stream>>>(o3, cw0, cb0, xg0);
    conv3x3_small_k<64, 64, 8, 8, 2><<<32, 256, 0, stream>>>(xg0, cw1, cb1, xg1);
    fc_k<<<BATCH, 256, 0, stream>>>(xg1, fw1, fb1, fw2, fb2, fw3, fb3, xgv);
    // bug fix (R3): grid must cover B*8*256 = 16384 threads -> 64 blocks, not 8.
    // (R3's 8-block launch left batches 1..7 of bg as 0xAA ws-poison = -3e-13,
    //  which matched the observed absmax 0.79296875 - 3.03e-13 exactly.)
    fuse_k<<<64, 256, 0, stream>>>(xgv, xl2, fuw, fub, bg);
    // highres guide + slice
    guide_slice_k<<<BATCH * 32 * 16, 256, 0, stream>>>(lqs, bg, gw1, gb1, gw2, gb2, out);
}

// Round 5
// 629.941 us; speedup vs baseline: 1.8345x; 1.1388x over previous
//
#include <hip/hip_runtime.h>
#include <hip/hip_bf16.h>
#include <math.h>

#define BATCH 8
#define HH 1024
#define WW 1024

__device__ __forceinline__ int reflect1024(int i) {
    i = i < 0 ? -i : i;
    return i > 1023 ? 2046 - i : i;
}

// ---------------------------------------------------------------------------
// conv0: input = concat(nearest_resize(lqs,256) [3ch], evs [15ch]) -> 18ch
//        (8,18,3,3) stride2 pad1 + bias + relu -> [B,8,128,128]
// Multi-OC: each thread computes ALL 8 output channels at one pixel.
// Weights read with wave-uniform indices -> compiler scalarizes to s_load.
// ---------------------------------------------------------------------------
__global__ __launch_bounds__(256) void conv0_k(const float* __restrict__ lqs,
                                               const float* __restrict__ evs,
                                               const float* __restrict__ w,
                                               const float* __restrict__ bias,
                                               float* __restrict__ out) {
    int idx = blockIdx.x * 256 + threadIdx.x;  // 131072 = 8 batches * 16384 px
    int p = idx & 16383;
    int b = idx >> 14;
    int ox = p & 127, oy = p >> 7;
    int iy0 = oy * 2 - 1, ix0 = ox * 2 - 1;

    float acc[8];
#pragma unroll
    for (int o = 0; o < 8; ++o) acc[o] = bias[o];

    // lqs channels (nearest-decimated by 4)
#pragma unroll
    for (int ic = 0; ic < 3; ++ic) {
        const float* ipc = lqs + (size_t)(b * 3 + ic) * HH * WW;
        float x[9];
#pragma unroll
        for (int ky = 0; ky < 3; ++ky) {
            int iy = iy0 + ky;
#pragma unroll
            for (int kx = 0; kx < 3; ++kx) {
                int ix = ix0 + kx;
                x[ky * 3 + kx] = (iy >= 0 && ix >= 0) ? ipc[(size_t)iy * 4 * WW + ix * 4] : 0.0f;
            }
        }
#pragma unroll
        for (int o = 0; o < 8; ++o) {
            const float* wp = w + (o * 18 + ic) * 9;
#pragma unroll
            for (int k = 0; k < 9; ++k) acc[o] = fmaf(wp[k], x[k], acc[o]);
        }
    }
    // evs channels
    for (int ic = 0; ic < 15; ++ic) {
        const float* ipc = evs + (size_t)(b * 15 + ic) * 65536;
        float x[9];
#pragma unroll
        for (int ky = 0; ky < 3; ++ky) {
            int iy = iy0 + ky;
#pragma unroll
            for (int kx = 0; kx < 3; ++kx) {
                int ix = ix0 + kx;
                x[ky * 3 + kx] = (iy >= 0 && ix >= 0) ? ipc[iy * 256 + ix] : 0.0f;
            }
        }
#pragma unroll
        for (int o = 0; o < 8; ++o) {
            const float* wp = w + (o * 18 + ic + 3) * 9;
#pragma unroll
            for (int k = 0; k < 9; ++k) acc[o] = fmaf(wp[k], x[k], acc[o]);
        }
    }
#pragma unroll
    for (int o = 0; o < 8; ++o)
        out[((size_t)(b * 8 + o) << 14) + p] = fmaxf(acc[o], 0.0f);
}

// ---------------------------------------------------------------------------
// generic 3x3 conv, pad=1: each thread computes OCT output channels at one
// pixel. Input loaded once into regs, reused OCT times. Weight indices are
// wave-uniform (b,g uniform per wave when OH*OW>=64) -> scalar loads.
// ---------------------------------------------------------------------------
template <int IC, int OC, int OCT, int IH, int IW, int STRIDE, bool RELU, bool HASB>
__global__ __launch_bounds__(256) void convN_k(const float* __restrict__ in,
                                               const float* __restrict__ w,
                                               const float* __restrict__ bias,
                                               float* __restrict__ out) {
    constexpr int OH = (IH + 2 - 3) / STRIDE + 1;
    constexpr int OW = (IW + 2 - 3) / STRIDE + 1;
    constexpr int POS = OH * OW;
    constexpr int G = OC / OCT;
    int idx = blockIdx.x * 256 + threadIdx.x;
    if (idx >= BATCH * G * POS) return;
    int px = idx % POS;
    int g = (idx / POS) % G;
    int b = idx / (POS * G);
    int ox = px % OW, oy = px / OW;
    int iy0 = oy * STRIDE - 1, ix0 = ox * STRIDE - 1;

    float acc[OCT];
#pragma unroll
    for (int o = 0; o < OCT; ++o) acc[o] = HASB ? bias[g * OCT + o] : 0.0f;

    const float* ip = in + (size_t)b * IC * IH * IW;
    for (int ic = 0; ic < IC; ++ic) {
        const float* ipc = ip + ic * IH * IW;
        float x[9];
#pragma unroll
        for (int ky = 0; ky < 3; ++ky) {
            int iy = iy0 + ky;
#pragma unroll
            for (int kx = 0; kx < 3; ++kx) {
                int ix = ix0 + kx;
                bool ok = (iy >= 0) && (iy < IH) && (ix >= 0) && (ix < IW);
                x[ky * 3 + kx] = ok ? ipc[iy * IW + ix] : 0.0f;
            }
        }
#pragma unroll
        for (int o = 0; o < OCT; ++o) {
            const float* wp = w + ((g * OCT + o) * IC + ic) * 9;
#pragma unroll
            for (int k = 0; k < 9; ++k) acc[o] = fmaf(wp[k], x[k], acc[o]);
        }
    }
#pragma unroll
    for (int o = 0; o < OCT; ++o) {
        float v = acc[o];
        if (RELU) v = fmaxf(v, 0.0f);
        out[(size_t)(b * OC + g * OCT + o) * POS + px] = v;
    }
}

// ---------------------------------------------------------------------------
// fused FC stack: [B,1024] -> 256 relu -> 128 relu -> 64. One block per batch.
// ---------------------------------------------------------------------------
__global__ __launch_bounds__(256) void fc_k(const float* __restrict__ xin_g,
                                            const float* __restrict__ fw1, const float* __restrict__ fb1,
                                            const float* __restrict__ fw2, const float* __restrict__ fb2,
                                            const float* __restrict__ fw3, const float* __restrict__ fb3,
                                            float* __restrict__ xg_out) {
    __shared__ float xin[1024];
    __shared__ float h1[256];
    __shared__ float h2[128];
    int b = blockIdx.x, t = threadIdx.x;
    for (int i = t; i < 1024; i += 256) xin[i] = xin_g[b * 1024 + i];
    __syncthreads();
    {
        float acc = fb1[t];
        const float* wr = fw1 + t * 1024;
#pragma unroll 8
        for (int k = 0; k < 1024; ++k) acc = fmaf(wr[k], xin[k], acc);
        h1[t] = fmaxf(acc, 0.0f);
    }
    __syncthreads();
    if (t < 128) {
        float acc = fb2[t];
        const float* wr = fw2 + t * 256;
#pragma unroll 8
        for (int k = 0; k < 256; ++k) acc = fmaf(wr[k], h1[k], acc);
        h2[t] = fmaxf(acc, 0.0f);
    }
    __syncthreads();
    if (t < 64) {
        float acc = fb3[t];
        const float* wr = fw3 + t * 128;
#pragma unroll 8
        for (int k = 0; k < 128; ++k) acc = fmaf(wr[k], h2[k], acc);
        xg_out[b * 64 + t] = acc;
    }
}

// ---------------------------------------------------------------------------
// fused = relu(xg[b,c] + xl[b,c,y,x]); bg[b,d,y,x] = sum_c fuw[d,c]*fused+fub
// ---------------------------------------------------------------------------
__global__ __launch_bounds__(256) void fuse_k(const float* __restrict__ xg,
                                              const float* __restrict__ xl,
                                              const float* __restrict__ fuw,
                                              const float* __restrict__ fub,
                                              float* __restrict__ bg) {
    int idx = blockIdx.x * blockDim.x + threadIdx.x;  // B*8*256
    if (idx >= BATCH * 8 * 256) return;
    int px = idx % 256;
    int d = (idx / 256) % 8;
    int b = idx / 2048;
    float acc = fub[d];
    for (int c = 0; c < 64; ++c) {
        float f = xg[b * 64 + c] + xl[(b * 64 + c) * 256 + px];
        f = fmaxf(f, 0.0f);
        acc = fmaf(fuw[d * 64 + c], f, acc);
    }
    bg[idx] = acc;
}

// ---------------------------------------------------------------------------
// guide+slice v2: vertical-first separable blur with sliding register
// windows, LDS 81-stride padding, per-px guide MLP + trilinear grid slice.
// Tile 64(x) x 32(y), 256 threads.
// ---------------------------------------------------------------------------
__global__ __launch_bounds__(256) void guide_slice_k(const float* __restrict__ lqs,
                                                     const float* __restrict__ bgp,
                                                     const float* __restrict__ gw1,
                                                     const float* __restrict__ gb1,
                                                     const float* __restrict__ gw2,
                                                     const float* __restrict__ gb2,
                                                     float* __restrict__ out) {
    constexpr int TW = 64, TH = 32;
    __shared__ float sBH[3][TH][81];  // vertically-blurred, 80 cols used (+1 pad)
    __shared__ float sBG[2048];       // bilateral grid [8][16][16]
    __shared__ float sW1[48], sB1[16], sW2[16], sB2v[1];

    int t = threadIdx.x;
    int bx = blockIdx.x & 15;         // WW/TW
    int by = (blockIdx.x >> 4) & 31;  // HH/TH
    int b = blockIdx.x >> 9;
    int x0 = bx * TW, y0 = by * TH;

    // gaussian weights (sigma=2, 17 taps), same formula as reference
    float gv[17];
    {
        float gs = 0.0f;
#pragma unroll
        for (int i = 0; i < 17; ++i) {
            float d = (float)i - 8.0f;
            gv[i] = expf(-(d * d) * 0.125f);
            gs += gv[i];
        }
        float inv = 1.0f / gs;
#pragma unroll
        for (int i = 0; i < 17; ++i) gv[i] *= inv;
    }

    for (int i = t; i < 2048; i += 256) sBG[i] = bgp[b * 2048 + i];
    if (t < 48) sW1[t] = gw1[t];
    if (t < 16) { sB1[t] = gb1[t]; sW2[t] = gw2[t]; }
    if (t == 0) sB2v[0] = gb2[0];

    // ---- stage 1: vertical blur, sliding window down each column ----
    if (t < 240) {
        int c = t / 80, xo = t % 80;
        int gx = reflect1024(x0 + xo - 8);
        const float* colp = lqs + (size_t)(b * 3 + c) * HH * WW + gx;
        float win[17];
#pragma unroll
        for (int i = 0; i < 16; ++i)
            win[i] = colp[(size_t)reflect1024(y0 - 8 + i) * WW];
#pragma unroll
        for (int j = 0; j < TH; ++j) {
            win[(16 + j) % 17] = colp[(size_t)reflect1024(y0 + 8 + j) * WW];
            float acc = 0.0f;
#pragma unroll
            for (int i = 0; i < 17; ++i) acc = fmaf(gv[i], win[(j + i) % 17], acc);
            sBH[c][j][xo] = acc;
        }
    }
    __syncthreads();

    // ---- stage 2: horizontal blur (sliding window), guide MLP, slice ----
    int yy = t >> 3, xs = (t & 7) * 8;  // 32 rows x 8 col-runs of 8
    int Y = y0 + yy;
    float fy = fminf(fmaxf((Y + 0.5f) * (1.0f / 64.0f) + 3.5f, 0.0f), 15.0f);
    float yf = floorf(fy);
    int yi = (int)yf;
    float ay = fy - yf;
    int yi1 = min(yi + 1, 15);

    float bcv[3][8];
#pragma unroll
    for (int c = 0; c < 3; ++c) {
        float win[17];
#pragma unroll
        for (int i = 0; i < 16; ++i) win[i] = sBH[c][yy][xs + i];
#pragma unroll
        for (int j = 0; j < 8; ++j) {
            win[(16 + j) % 17] = sBH[c][yy][xs + 16 + j];
            float acc = 0.0f;
#pragma unroll
            for (int i = 0; i < 17; ++i) acc = fmaf(gv[i], win[(j + i) % 17], acc);
            bcv[c][j] = acc;
        }
    }

    float val[8];
#pragma unroll
    for (int j = 0; j < 8; ++j) {
        float b0 = bcv[0][j], b1 = bcv[1][j], b2 = bcv[2][j];
        float s = sB2v[0];
#pragma unroll
        for (int c = 0; c < 16; ++c) {
            float g1 = fmaf(sW1[c * 3 + 0], b0,
                       fmaf(sW1[c * 3 + 1], b1,
                       fmaf(sW1[c * 3 + 2], b2, sB1[c])));
            s = fmaf(sW2[c], fmaxf(g1, 0.0f), s);
        }
        float sig = 1.0f / (1.0f + expf(-s));
        float guide = sig * 2.0f - 0.5f;

        int X = x0 + xs + j;
        float fx = fminf(fmaxf((X + 0.5f) * (1.0f / 64.0f) + 3.5f, 0.0f), 15.0f);
        float fz = fminf(fmaxf(fmaf(guide, 4.0f, 3.5f), 0.0f), 7.0f);
        float xf = floorf(fx), zf = floorf(fz);
        int xi = (int)xf, zi = (int)zf;
        float ax = fx - xf, az = fz - zf;
        int xi1 = min(xi + 1, 15), zi1 = min(zi + 1, 7);

        const float* g0 = sBG + zi * 256;
        const float* g1p = sBG + zi1 * 256;
        int i00 = yi * 16 + xi, i01 = yi * 16 + xi1;
        int i10 = yi1 * 16 + xi, i11 = yi1 * 16 + xi1;
        float c00 = g0[i00] + az * (g1p[i00] - g0[i00]);
        float c01 = g0[i01] + az * (g1p[i01] - g0[i01]);
        float c10 = g0[i10] + az * (g1p[i10] - g0[i10]);
        float c11 = g0[i11] + az * (g1p[i11] - g0[i11]);
        float c0 = c00 + ay * (c10 - c00);
        float c1 = c01 + ay * (c11 - c01);
        val[j] = c0 + ax * (c1 - c0);
    }
    float4* op = (float4*)(out + (size_t)b * HH * WW + (size_t)Y * WW + x0 + xs);
    op[0] = make_float4(val[0], val[1], val[2], val[3]);
    op[1] = make_float4(val[4], val[5], val[6], val[7]);
}

// ---------------------------------------------------------------------------
extern "C" void kernel_launch(void* const* d_in, const int* in_sizes, int n_in,
                              void* d_out, int out_size, void* d_ws, size_t ws_size,
                              hipStream_t stream) {
    const float* lqs = (const float*)d_in[0];
    const float* evs = (const float*)d_in[1];
    const float* gw1 = (const float*)d_in[2];
    const float* gb1 = (const float*)d_in[3];
    const float* gw2 = (const float*)d_in[4];
    const float* gb2 = (const float*)d_in[5];
    const float* sw0 = (const float*)d_in[6];
    const float* sb0 = (const float*)d_in[7];
    const float* sw1 = (const float*)d_in[8];
    const float* sb1 = (const float*)d_in[9];
    const float* sw2 = (const float*)d_in[10];
    const float* sb2 = (const float*)d_in[11];
    const float* sw3 = (const float*)d_in[12];
    const float* sb3 = (const float*)d_in[13];
    const float* cw0 = (const float*)d_in[14];
    const float* cb0 = (const float*)d_in[15];
    const float* cw1 = (const float*)d_in[16];
    const float* cb1 = (const float*)d_in[17];
    const float* fw1 = (const float*)d_in[18];
    const float* fb1 = (const float*)d_in[19];
    const float* fw2 = (const float*)d_in[20];
    const float* fb2 = (const float*)d_in[21];
    const float* fw3 = (const float*)d_in[22];
    const float* fb3 = (const float*)d_in[23];
    const float* lw1 = (const float*)d_in[24];
    const float* lb1 = (const float*)d_in[25];
    const float* lw2 = (const float*)d_in[26];
    const float* fuw = (const float*)d_in[27];
    const float* fub = (const float*)d_in[28];
    float* out = (float*)d_out;

    float* ws = (float*)d_ws;
    float* o0 = ws;             // [8,8,128,128]   1048576
    float* o1 = o0 + 1048576;   // [8,16,64,64]     524288
    float* o2 = o1 + 524288;    // [8,32,32,32]     262144
    float* o3 = o2 + 262144;    // [8,64,16,16]     131072
    float* xl1 = o3 + 131072;   // [8,64,16,16]     131072
    float* xl2 = xl1 + 131072;  // [8,64,16,16]     131072
    float* xg0 = xl2 + 131072;  // [8,64,8,8]        32768
    float* xg1 = xg0 + 32768;   // [8,64,4,4]         8192
    float* xgv = xg1 + 8192;    // [8,64]              512
    float* bg = xgv + 512;      // [8,8,16,16]       16384

    // lowres stream (multi-OC conv: input regs reused across output channels)
    conv0_k<<<512, 256, 0, stream>>>(lqs, evs, sw0, sb0, o0);
    convN_k<8, 16, 16, 128, 128, 2, true, true><<<128, 256, 0, stream>>>(o0, sw1, sb1, o1);
    convN_k<16, 32, 8, 64, 64, 2, true, true><<<128, 256, 0, stream>>>(o1, sw2, sb2, o2);
    convN_k<32, 64, 8, 32, 32, 2, true, true><<<64, 256, 0, stream>>>(o2, sw3, sb3, o3);
    // local path
    convN_k<64, 64, 8, 16, 16, 1, true, true><<<64, 256, 0, stream>>>(o3, lw1, lb1, xl1);
    convN_k<64, 64, 8, 16, 16, 1, false, false><<<64, 256, 0, stream>>>(xl1, lw2, nullptr, xl2);
    // global path
    convN_k<64, 64, 8, 16, 16, 2, true, true><<<16, 256, 0, stream>>>(o3, cw0, cb0, xg0);
    convN_k<64, 64, 8, 8, 8, 2, true, true><<<4, 256, 0, stream>>>(xg0, cw1, cb1, xg1);
    fc_k<<<BATCH, 256, 0, stream>>>(xg1, fw1, fb1, fw2, fb2, fw3, fb3, xgv);
    // grid must cover B*8*256 = 16384 threads -> 64 blocks (R3 bug: 8 blocks
    // left batches 1..7 of bg as ws-poison).
    fuse_k<<<64, 256, 0, stream>>>(xgv, xl2, fuw, fub, bg);
    // highres guide + slice
    guide_slice_k<<<BATCH * 32 * 16, 256, 0, stream>>>(lqs, bg, gw1, gb1, gw2, gb2, out);
}

// Round 6
// 506.177 us; speedup vs baseline: 2.2831x; 1.2445x over previous
//
#include <hip/hip_runtime.h>
#include <hip/hip_bf16.h>
#include <math.h>

#define BATCH 8
#define HH 1024
#define WW 1024

__device__ __forceinline__ int reflect1024(int i) {
    i = i < 0 ? -i : i;
    return i > 1023 ? 2046 - i : i;
}

// ---------------------------------------------------------------------------
// conv0 v2: concat(nearest_resize(lqs,256)[3], evs[15]) -> (8,18,3,3) s2 p1
// + bias + relu -> [B,8,128,128].  4 output px along x per thread:
// evs taps = 2 aligned float4 + 1 scalar per (ic,ky); weights scalarized
// (wave-uniform). 32768 threads.
// ---------------------------------------------------------------------------
__global__ __launch_bounds__(256) void conv0_k(const float* __restrict__ lqs,
                                               const float* __restrict__ evs,
                                               const float* __restrict__ w,
                                               const float* __restrict__ bias,
                                               float* __restrict__ out) {
    int idx = blockIdx.x * 256 + threadIdx.x;  // B * 4096
    int q = idx & 4095;
    int b = idx >> 12;
    int qx = q & 31, oy = q >> 5;  // 32 groups of 4 px per row
    int iy0 = oy * 2 - 1;

    float acc[4][8];
#pragma unroll
    for (int j = 0; j < 4; ++j)
#pragma unroll
        for (int o = 0; o < 8; ++o) acc[j][o] = bias[o];

    // lqs channels (decimated x4); scattered gathers but only 3/18 channels
#pragma unroll
    for (int ic = 0; ic < 3; ++ic) {
        const float* ipc = lqs + (size_t)(b * 3 + ic) * HH * WW;
#pragma unroll
        for (int ky = 0; ky < 3; ++ky) {
            int iy = iy0 + ky;
            if (iy < 0) continue;
            const float* row = ipc + (size_t)iy * 4 * WW;
            float xr[9];
#pragma unroll
            for (int i = 0; i < 9; ++i) {
                int ix = 8 * qx - 1 + i;
                xr[i] = (ix >= 0) ? row[ix * 4] : 0.0f;
            }
#pragma unroll
            for (int o = 0; o < 8; ++o) {
                const float* wp = w + (o * 18 + ic) * 9 + ky * 3;
#pragma unroll
                for (int j = 0; j < 4; ++j)
#pragma unroll
                    for (int kx = 0; kx < 3; ++kx)
                        acc[j][o] = fmaf(wp[kx], xr[2 * j + kx], acc[j][o]);
            }
        }
    }
    // evs channels: vector loads
    for (int ic = 0; ic < 15; ++ic) {
        const float* ipc = evs + (size_t)(b * 15 + ic) * 65536;
#pragma unroll
        for (int ky = 0; ky < 3; ++ky) {
            int iy = iy0 + ky;
            if (iy < 0) continue;
            const float* row = ipc + iy * 256;
            const float4* r4 = (const float4*)row;
            float4 A = r4[2 * qx];
            float4 Bv = r4[2 * qx + 1];
            float m = (qx > 0) ? row[8 * qx - 1] : 0.0f;
            float xr[9] = {m, A.x, A.y, A.z, A.w, Bv.x, Bv.y, Bv.z, Bv.w};
#pragma unroll
            for (int o = 0; o < 8; ++o) {
                const float* wp = w + (o * 18 + ic + 3) * 9 + ky * 3;
#pragma unroll
                for (int j = 0; j < 4; ++j)
#pragma unroll
                    for (int kx = 0; kx < 3; ++kx)
                        acc[j][o] = fmaf(wp[kx], xr[2 * j + kx], acc[j][o]);
            }
        }
    }
#pragma unroll
    for (int o = 0; o < 8; ++o) {
        float4 v = make_float4(fmaxf(acc[0][o], 0.0f), fmaxf(acc[1][o], 0.0f),
                               fmaxf(acc[2][o], 0.0f), fmaxf(acc[3][o], 0.0f));
        *(float4*)(out + ((size_t)(b * 8 + o) << 14) + oy * 128 + qx * 4) = v;
    }
}

// ---------------------------------------------------------------------------
// generic 3x3 conv (unsplit), pad=1, OCT output channels per thread.
// ---------------------------------------------------------------------------
template <int IC, int OC, int OCT, int IH, int IW, int STRIDE, bool RELU, bool HASB>
__global__ __launch_bounds__(256) void convN_k(const float* __restrict__ in,
                                               const float* __restrict__ w,
                                               const float* __restrict__ bias,
                                               float* __restrict__ out) {
    constexpr int OH = (IH + 2 - 3) / STRIDE + 1;
    constexpr int OW = (IW + 2 - 3) / STRIDE + 1;
    constexpr int POS = OH * OW;
    constexpr int G = OC / OCT;
    int idx = blockIdx.x * 256 + threadIdx.x;
    if (idx >= BATCH * G * POS) return;
    int px = idx % POS;
    int g = (idx / POS) % G;
    int b = idx / (POS * G);
    int ox = px % OW, oy = px / OW;
    int iy0 = oy * STRIDE - 1, ix0 = ox * STRIDE - 1;

    float acc[OCT];
#pragma unroll
    for (int o = 0; o < OCT; ++o) acc[o] = HASB ? bias[g * OCT + o] : 0.0f;

    const float* ip = in + (size_t)b * IC * IH * IW;
    for (int ic = 0; ic < IC; ++ic) {
        const float* ipc = ip + ic * IH * IW;
        float x[9];
#pragma unroll
        for (int ky = 0; ky < 3; ++ky) {
            int iy = iy0 + ky;
#pragma unroll
            for (int kx = 0; kx < 3; ++kx) {
                int ix = ix0 + kx;
                bool ok = (iy >= 0) && (iy < IH) && (ix >= 0) && (ix < IW);
                x[ky * 3 + kx] = ok ? ipc[iy * IW + ix] : 0.0f;
            }
        }
#pragma unroll
        for (int o = 0; o < OCT; ++o) {
            const float* wp = w + ((g * OCT + o) * IC + ic) * 9;
#pragma unroll
            for (int k = 0; k < 9; ++k) acc[o] = fmaf(wp[k], x[k], acc[o]);
        }
    }
#pragma unroll
    for (int o = 0; o < OCT; ++o) {
        float v = acc[o];
        if (RELU) v = fmaxf(v, 0.0f);
        out[(size_t)(b * OC + g * OCT + o) * POS + px] = v;
    }
}

// ---------------------------------------------------------------------------
// split-K 3x3 conv: SPLIT partial IC-range sums into part[]; no bias/relu
// (applied by reduce_k). SPLIT x more threads for latency hiding.
// ---------------------------------------------------------------------------
template <int IC, int OC, int OCT, int IH, int IW, int STRIDE, int SPLIT>
__global__ __launch_bounds__(256) void convS_k(const float* __restrict__ in,
                                               const float* __restrict__ w,
                                               float* __restrict__ part) {
    constexpr int OH = (IH + 2 - 3) / STRIDE + 1;
    constexpr int OW = (IW + 2 - 3) / STRIDE + 1;
    constexpr int POS = OH * OW;
    constexpr int G = OC / OCT;
    constexpr int TOT = BATCH * G * POS;
    constexpr int ICS = IC / SPLIT;
    constexpr int N = BATCH * OC * POS;
    int idx = blockIdx.x * 256 + threadIdx.x;
    if (idx >= TOT * SPLIT) return;
    int s = idx / TOT, r = idx % TOT;
    int px = r % POS;
    int g = (r / POS) % G;
    int b = r / (POS * G);
    int ox = px % OW, oy = px / OW;
    int iy0 = oy * STRIDE - 1, ix0 = ox * STRIDE - 1;

    float acc[OCT];
#pragma unroll
    for (int o = 0; o < OCT; ++o) acc[o] = 0.0f;

    const float* ip = in + (size_t)b * IC * IH * IW;
    for (int ic = s * ICS; ic < (s + 1) * ICS; ++ic) {
        const float* ipc = ip + ic * IH * IW;
        float x[9];
#pragma unroll
        for (int ky = 0; ky < 3; ++ky) {
            int iy = iy0 + ky;
#pragma unroll
            for (int kx = 0; kx < 3; ++kx) {
                int ix = ix0 + kx;
                bool ok = (iy >= 0) && (iy < IH) && (ix >= 0) && (ix < IW);
                x[ky * 3 + kx] = ok ? ipc[iy * IW + ix] : 0.0f;
            }
        }
#pragma unroll
        for (int o = 0; o < OCT; ++o) {
            const float* wp = w + ((g * OCT + o) * IC + ic) * 9;
#pragma unroll
            for (int k = 0; k < 9; ++k) acc[o] = fmaf(wp[k], x[k], acc[o]);
        }
    }
#pragma unroll
    for (int o = 0; o < OCT; ++o)
        part[(size_t)s * N + (size_t)(b * OC + g * OCT + o) * POS + px] = acc[o];
}

// ---------------------------------------------------------------------------
// reduce split-K partials + bias + relu
// ---------------------------------------------------------------------------
template <int OC, int POS, int SPLIT, bool RELU, bool HASB>
__global__ __launch_bounds__(256) void reduce_k(const float* __restrict__ part,
                                                const float* __restrict__ bias,
                                                float* __restrict__ out) {
    constexpr int N = BATCH * OC * POS;
    int idx = blockIdx.x * 256 + threadIdx.x;
    if (idx >= N) return;
    int oc = (idx / POS) % OC;
    float a = HASB ? bias[oc] : 0.0f;
#pragma unroll
    for (int s = 0; s < SPLIT; ++s) a += part[(size_t)s * N + idx];
    out[idx] = RELU ? fmaxf(a, 0.0f) : a;
}

// ---------------------------------------------------------------------------
// fc v2: lane-split-K + shfl_xor tree reduction; coalesced float4 weight
// reads. One block per batch; wave w owns a row range.
// ---------------------------------------------------------------------------
__global__ __launch_bounds__(256) void fc_k(const float* __restrict__ xin_g,
                                            const float* __restrict__ fw1, const float* __restrict__ fb1,
                                            const float* __restrict__ fw2, const float* __restrict__ fb2,
                                            const float* __restrict__ fw3, const float* __restrict__ fb3,
                                            float* __restrict__ xg_out) {
    __shared__ float xin[1024];
    __shared__ float h1[256];
    __shared__ float h2[128];
    int b = blockIdx.x, t = threadIdx.x;
    int wave = t >> 6, lane = t & 63;
    ((float4*)xin)[t] = ((const float4*)(xin_g + b * 1024))[t];
    __syncthreads();

    const float4* xin4 = (const float4*)xin;
#pragma unroll 4
    for (int i = 0; i < 64; ++i) {
        int r = wave * 64 + i;
        const float4* w4 = (const float4*)(fw1 + r * 1024);
        float acc = 0.0f;
#pragma unroll
        for (int jj = 0; jj < 4; ++jj) {
            float4 wv = w4[lane + 64 * jj];
            float4 xv = xin4[lane + 64 * jj];
            acc = fmaf(wv.x, xv.x, acc);
            acc = fmaf(wv.y, xv.y, acc);
            acc = fmaf(wv.z, xv.z, acc);
            acc = fmaf(wv.w, xv.w, acc);
        }
#pragma unroll
        for (int m = 32; m; m >>= 1) acc += __shfl_xor(acc, m, 64);
        if (lane == 0) h1[r] = fmaxf(acc + fb1[r], 0.0f);
    }
    __syncthreads();

    const float4* h14 = (const float4*)h1;
#pragma unroll 4
    for (int i = 0; i < 32; ++i) {
        int r = wave * 32 + i;
        const float4* w4 = (const float4*)(fw2 + r * 256);
        float4 wv = w4[lane];
        float4 xv = h14[lane];
        float acc = fmaf(wv.x, xv.x, fmaf(wv.y, xv.y, fmaf(wv.z, xv.z, wv.w * xv.w)));
#pragma unroll
        for (int m = 32; m; m >>= 1) acc += __shfl_xor(acc, m, 64);
        if (lane == 0) h2[r] = fmaxf(acc + fb2[r], 0.0f);
    }
    __syncthreads();

    const float2* h22 = (const float2*)h2;
#pragma unroll 4
    for (int i = 0; i < 16; ++i) {
        int r = wave * 16 + i;
        const float2* w2 = (const float2*)(fw3 + r * 128);
        float2 wv = w2[lane];
        float2 xv = h22[lane];
        float acc = fmaf(wv.x, xv.x, wv.y * xv.y);
#pragma unroll
        for (int m = 32; m; m >>= 1) acc += __shfl_xor(acc, m, 64);
        if (lane == 0) xg_out[b * 64 + r] = acc + fb3[r];
    }
}

// ---------------------------------------------------------------------------
// fused = relu(xg[b,c] + xl[b,c,y,x]); bg[b,d,y,x] = sum_c fuw[d,c]*fused+fub
// ---------------------------------------------------------------------------
__global__ __launch_bounds__(256) void fuse_k(const float* __restrict__ xg,
                                              const float* __restrict__ xl,
                                              const float* __restrict__ fuw,
                                              const float* __restrict__ fub,
                                              float* __restrict__ bg) {
    int idx = blockIdx.x * blockDim.x + threadIdx.x;  // B*8*256
    if (idx >= BATCH * 8 * 256) return;
    int px = idx % 256;
    int d = (idx / 256) % 8;
    int b = idx / 2048;
    float acc = fub[d];
    for (int c = 0; c < 64; ++c) {
        float f = xg[b * 64 + c] + xl[(b * 64 + c) * 256 + px];
        f = fmaxf(f, 0.0f);
        acc = fmaf(fuw[d * 64 + c], f, acc);
    }
    bg[idx] = acc;
}

// ---------------------------------------------------------------------------
// guide+slice (unchanged from R5): vertical-first separable blur, sliding
// register windows, per-px guide MLP + trilinear grid slice.
// ---------------------------------------------------------------------------
__global__ __launch_bounds__(256) void guide_slice_k(const float* __restrict__ lqs,
                                                     const float* __restrict__ bgp,
                                                     const float* __restrict__ gw1,
                                                     const float* __restrict__ gb1,
                                                     const float* __restrict__ gw2,
                                                     const float* __restrict__ gb2,
                                                     float* __restrict__ out) {
    constexpr int TW = 64, TH = 32;
    __shared__ float sBH[3][TH][81];
    __shared__ float sBG[2048];
    __shared__ float sW1[48], sB1[16], sW2[16], sB2v[1];

    int t = threadIdx.x;
    int bx = blockIdx.x & 15;
    int by = (blockIdx.x >> 4) & 31;
    int b = blockIdx.x >> 9;
    int x0 = bx * TW, y0 = by * TH;

    float gv[17];
    {
        float gs = 0.0f;
#pragma unroll
        for (int i = 0; i < 17; ++i) {
            float d = (float)i - 8.0f;
            gv[i] = expf(-(d * d) * 0.125f);
            gs += gv[i];
        }
        float inv = 1.0f / gs;
#pragma unroll
        for (int i = 0; i < 17; ++i) gv[i] *= inv;
    }

    for (int i = t; i < 2048; i += 256) sBG[i] = bgp[b * 2048 + i];
    if (t < 48) sW1[t] = gw1[t];
    if (t < 16) { sB1[t] = gb1[t]; sW2[t] = gw2[t]; }
    if (t == 0) sB2v[0] = gb2[0];

    if (t < 240) {
        int c = t / 80, xo = t % 80;
        int gx = reflect1024(x0 + xo - 8);
        const float* colp = lqs + (size_t)(b * 3 + c) * HH * WW + gx;
        float win[17];
#pragma unroll
        for (int i = 0; i < 16; ++i)
            win[i] = colp[(size_t)reflect1024(y0 - 8 + i) * WW];
#pragma unroll
        for (int j = 0; j < TH; ++j) {
            win[(16 + j) % 17] = colp[(size_t)reflect1024(y0 + 8 + j) * WW];
            float acc = 0.0f;
#pragma unroll
            for (int i = 0; i < 17; ++i) acc = fmaf(gv[i], win[(j + i) % 17], acc);
            sBH[c][j][xo] = acc;
        }
    }
    __syncthreads();

    int yy = t >> 3, xs = (t & 7) * 8;
    int Y = y0 + yy;
    float fy = fminf(fmaxf((Y + 0.5f) * (1.0f / 64.0f) + 3.5f, 0.0f), 15.0f);
    float yf = floorf(fy);
    int yi = (int)yf;
    float ay = fy - yf;
    int yi1 = min(yi + 1, 15);

    float bcv[3][8];
#pragma unroll
    for (int c = 0; c < 3; ++c) {
        float win[17];
#pragma unroll
        for (int i = 0; i < 16; ++i) win[i] = sBH[c][yy][xs + i];
#pragma unroll
        for (int j = 0; j < 8; ++j) {
            win[(16 + j) % 17] = sBH[c][yy][xs + 16 + j];
            float acc = 0.0f;
#pragma unroll
            for (int i = 0; i < 17; ++i) acc = fmaf(gv[i], win[(j + i) % 17], acc);
            bcv[c][j] = acc;
        }
    }

    float val[8];
#pragma unroll
    for (int j = 0; j < 8; ++j) {
        float b0 = bcv[0][j], b1 = bcv[1][j], b2 = bcv[2][j];
        float s = sB2v[0];
#pragma unroll
        for (int c = 0; c < 16; ++c) {
            float g1 = fmaf(sW1[c * 3 + 0], b0,
                       fmaf(sW1[c * 3 + 1], b1,
                       fmaf(sW1[c * 3 + 2], b2, sB1[c])));
            s = fmaf(sW2[c], fmaxf(g1, 0.0f), s);
        }
        float sig = 1.0f / (1.0f + expf(-s));
        float guide = sig * 2.0f - 0.5f;

        int X = x0 + xs + j;
        float fx = fminf(fmaxf((X + 0.5f) * (1.0f / 64.0f) + 3.5f, 0.0f), 15.0f);
        float fz = fminf(fmaxf(fmaf(guide, 4.0f, 3.5f), 0.0f), 7.0f);
        float xf = floorf(fx), zf = floorf(fz);
        int xi = (int)xf, zi = (int)zf;
        float ax = fx - xf, az = fz - zf;
        int xi1 = min(xi + 1, 15), zi1 = min(zi + 1, 7);

        const float* g0 = sBG + zi * 256;
        const float* g1p = sBG + zi1 * 256;
        int i00 = yi * 16 + xi, i01 = yi * 16 + xi1;
        int i10 = yi1 * 16 + xi, i11 = yi1 * 16 + xi1;
        float c00 = g0[i00] + az * (g1p[i00] - g0[i00]);
        float c01 = g0[i01] + az * (g1p[i01] - g0[i01]);
        float c10 = g0[i10] + az * (g1p[i10] - g0[i10]);
        float c11 = g0[i11] + az * (g1p[i11] - g0[i11]);
        float c0 = c00 + ay * (c10 - c00);
        float c1 = c01 + ay * (c11 - c01);
        val[j] = c0 + ax * (c1 - c0);
    }
    float4* op = (float4*)(out + (size_t)b * HH * WW + (size_t)Y * WW + x0 + xs);
    op[0] = make_float4(val[0], val[1], val[2], val[3]);
    op[1] = make_float4(val[4], val[5], val[6], val[7]);
}

// ---------------------------------------------------------------------------
extern "C" void kernel_launch(void* const* d_in, const int* in_sizes, int n_in,
                              void* d_out, int out_size, void* d_ws, size_t ws_size,
                              hipStream_t stream) {
    const float* lqs = (const float*)d_in[0];
    const float* evs = (const float*)d_in[1];
    const float* gw1 = (const float*)d_in[2];
    const float* gb1 = (const float*)d_in[3];
    const float* gw2 = (const float*)d_in[4];
    const float* gb2 = (const float*)d_in[5];
    const float* sw0 = (const float*)d_in[6];
    const float* sb0 = (const float*)d_in[7];
    const float* sw1 = (const float*)d_in[8];
    const float* sb1 = (const float*)d_in[9];
    const float* sw2 = (const float*)d_in[10];
    const float* sb2 = (const float*)d_in[11];
    const float* sw3 = (const float*)d_in[12];
    const float* sb3 = (const float*)d_in[13];
    const float* cw0 = (const float*)d_in[14];
    const float* cb0 = (const float*)d_in[15];
    const float* cw1 = (const float*)d_in[16];
    const float* cb1 = (const float*)d_in[17];
    const float* fw1 = (const float*)d_in[18];
    const float* fb1 = (const float*)d_in[19];
    const float* fw2 = (const float*)d_in[20];
    const float* fb2 = (const float*)d_in[21];
    const float* fw3 = (const float*)d_in[22];
    const float* fb3 = (const float*)d_in[23];
    const float* lw1 = (const float*)d_in[24];
    const float* lb1 = (const float*)d_in[25];
    const float* lw2 = (const float*)d_in[26];
    const float* fuw = (const float*)d_in[27];
    const float* fub = (const float*)d_in[28];
    float* out = (float*)d_out;

    float* ws = (float*)d_ws;
    float* o0 = ws;             // [8,8,128,128]   1048576
    float* o1 = o0 + 1048576;   // [8,16,64,64]     524288
    float* o2 = o1 + 524288;    // [8,32,32,32]     262144
    float* o3 = o2 + 262144;    // [8,64,16,16]     131072
    float* xl1 = o3 + 131072;   // [8,64,16,16]     131072
    float* xl2 = xl1 + 131072;  // [8,64,16,16]     131072
    float* xg0 = xl2 + 131072;  // [8,64,8,8]        32768
    float* xg1 = xg0 + 32768;   // [8,64,4,4]         8192
    float* xgv = xg1 + 8192;    // [8,64]              512
    float* bg = xgv + 512;      // [8,8,16,16]       16384
    float* part = bg + 16384;   // split-K partials (max 524288), reused
    // total ws: ~2.81M floats = 11.3 MB

    conv0_k<<<128, 256, 0, stream>>>(lqs, evs, sw0, sb0, o0);
    convN_k<8, 16, 16, 128, 128, 2, true, true><<<128, 256, 0, stream>>>(o0, sw1, sb1, o1);
    // conv2: 16->32 @64x64, split 2  (TOT 32768 -> 65536 threads)
    convS_k<16, 32, 8, 64, 64, 2, 2><<<256, 256, 0, stream>>>(o1, sw2, part);
    reduce_k<32, 1024, 2, true, true><<<1024, 256, 0, stream>>>(part, sb2, o2);
    // conv3: 32->64 @32x32, split 4
    convS_k<32, 64, 8, 32, 32, 2, 4><<<256, 256, 0, stream>>>(o2, sw3, part);
    reduce_k<64, 256, 4, true, true><<<512, 256, 0, stream>>>(part, sb3, o3);
    // local path: 64->64 @16x16, split 4
    convS_k<64, 64, 8, 16, 16, 1, 4><<<256, 256, 0, stream>>>(o3, lw1, part);
    reduce_k<64, 256, 4, true, true><<<512, 256, 0, stream>>>(part, lb1, xl1);
    convS_k<64, 64, 8, 16, 16, 1, 4><<<256, 256, 0, stream>>>(xl1, lw2, part);
    reduce_k<64, 256, 4, false, false><<<512, 256, 0, stream>>>(part, nullptr, xl2);
    // global path: split 8
    convS_k<64, 64, 8, 16, 16, 2, 8><<<128, 256, 0, stream>>>(o3, cw0, part);
    reduce_k<64, 64, 8, true, true><<<128, 256, 0, stream>>>(part, cb0, xg0);
    convS_k<64, 64, 8, 8, 8, 2, 8><<<32, 256, 0, stream>>>(xg0, cw1, part);
    reduce_k<64, 16, 8, true, true><<<32, 256, 0, stream>>>(part, cb1, xg1);
    fc_k<<<BATCH, 256, 0, stream>>>(xg1, fw1, fb1, fw2, fb2, fw3, fb3, xgv);
    fuse_k<<<64, 256, 0, stream>>>(xgv, xl2, fuw, fub, bg);
    guide_slice_k<<<BATCH * 32 * 16, 256, 0, stream>>>(lqs, bg, gw1, gb1, gw2, gb2, out);
}

// Round 7
// 400.230 us; speedup vs baseline: 2.8875x; 1.2647x over previous
//
#include <hip/hip_runtime.h>
#include <hip/hip_bf16.h>
#include <math.h>

#define BATCH 8
#define HH 1024
#define WW 1024

__device__ __forceinline__ int reflect1024(int i) {
    i = i < 0 ? -i : i;
    return i > 1023 ? 2046 - i : i;
}

// ---------------------------------------------------------------------------
// conv0: concat(nearest_resize(lqs,256)[3], evs[15]) -> (8,18,3,3) s2 p1
// + bias + relu -> [B,8,128,128]. 4 output px along x per thread.
// ---------------------------------------------------------------------------
__global__ __launch_bounds__(256) void conv0_k(const float* __restrict__ lqs,
                                               const float* __restrict__ evs,
                                               const float* __restrict__ w,
                                               const float* __restrict__ bias,
                                               float* __restrict__ out) {
    int idx = blockIdx.x * 256 + threadIdx.x;  // B * 4096
    int q = idx & 4095;
    int b = idx >> 12;
    int qx = q & 31, oy = q >> 5;
    int iy0 = oy * 2 - 1;

    float acc[4][8];
#pragma unroll
    for (int j = 0; j < 4; ++j)
#pragma unroll
        for (int o = 0; o < 8; ++o) acc[j][o] = bias[o];

#pragma unroll
    for (int ic = 0; ic < 3; ++ic) {
        const float* ipc = lqs + (size_t)(b * 3 + ic) * HH * WW;
#pragma unroll
        for (int ky = 0; ky < 3; ++ky) {
            int iy = iy0 + ky;
            if (iy < 0) continue;
            const float* row = ipc + (size_t)iy * 4 * WW;
            float xr[9];
#pragma unroll
            for (int i = 0; i < 9; ++i) {
                int ix = 8 * qx - 1 + i;
                xr[i] = (ix >= 0) ? row[ix * 4] : 0.0f;
            }
#pragma unroll
            for (int o = 0; o < 8; ++o) {
                const float* wp = w + (o * 18 + ic) * 9 + ky * 3;
#pragma unroll
                for (int j = 0; j < 4; ++j)
#pragma unroll
                    for (int kx = 0; kx < 3; ++kx)
                        acc[j][o] = fmaf(wp[kx], xr[2 * j + kx], acc[j][o]);
            }
        }
    }
    for (int ic = 0; ic < 15; ++ic) {
        const float* ipc = evs + (size_t)(b * 15 + ic) * 65536;
#pragma unroll
        for (int ky = 0; ky < 3; ++ky) {
            int iy = iy0 + ky;
            if (iy < 0) continue;
            const float* row = ipc + iy * 256;
            const float4* r4 = (const float4*)row;
            float4 A = r4[2 * qx];
            float4 Bv = r4[2 * qx + 1];
            float m = (qx > 0) ? row[8 * qx - 1] : 0.0f;
            float xr[9] = {m, A.x, A.y, A.z, A.w, Bv.x, Bv.y, Bv.z, Bv.w};
#pragma unroll
            for (int o = 0; o < 8; ++o) {
                const float* wp = w + (o * 18 + ic + 3) * 9 + ky * 3;
#pragma unroll
                for (int j = 0; j < 4; ++j)
#pragma unroll
                    for (int kx = 0; kx < 3; ++kx)
                        acc[j][o] = fmaf(wp[kx], xr[2 * j + kx], acc[j][o]);
            }
        }
    }
#pragma unroll
    for (int o = 0; o < 8; ++o) {
        float4 v = make_float4(fmaxf(acc[0][o], 0.0f), fmaxf(acc[1][o], 0.0f),
                               fmaxf(acc[2][o], 0.0f), fmaxf(acc[3][o], 0.0f));
        *(float4*)(out + ((size_t)(b * 8 + o) << 14) + oy * 128 + qx * 4) = v;
    }
}

// ---------------------------------------------------------------------------
// generic 3x3 conv (unsplit), pad=1, OCT output channels per thread.
// ---------------------------------------------------------------------------
template <int IC, int OC, int OCT, int IH, int IW, int STRIDE, bool RELU, bool HASB>
__global__ __launch_bounds__(256) void convN_k(const float* __restrict__ in,
                                               const float* __restrict__ w,
                                               const float* __restrict__ bias,
                                               float* __restrict__ out) {
    constexpr int OH = (IH + 2 - 3) / STRIDE + 1;
    constexpr int OW = (IW + 2 - 3) / STRIDE + 1;
    constexpr int POS = OH * OW;
    constexpr int G = OC / OCT;
    int idx = blockIdx.x * 256 + threadIdx.x;
    if (idx >= BATCH * G * POS) return;
    int px = idx % POS;
    int g = (idx / POS) % G;
    int b = idx / (POS * G);
    int ox = px % OW, oy = px / OW;
    int iy0 = oy * STRIDE - 1, ix0 = ox * STRIDE - 1;

    float acc[OCT];
#pragma unroll
    for (int o = 0; o < OCT; ++o) acc[o] = HASB ? bias[g * OCT + o] : 0.0f;

    const float* ip = in + (size_t)b * IC * IH * IW;
    for (int ic = 0; ic < IC; ++ic) {
        const float* ipc = ip + ic * IH * IW;
        float x[9];
#pragma unroll
        for (int ky = 0; ky < 3; ++ky) {
            int iy = iy0 + ky;
#pragma unroll
            for (int kx = 0; kx < 3; ++kx) {
                int ix = ix0 + kx;
                bool ok = (iy >= 0) && (iy < IH) && (ix >= 0) && (ix < IW);
                x[ky * 3 + kx] = ok ? ipc[iy * IW + ix] : 0.0f;
            }
        }
#pragma unroll
        for (int o = 0; o < OCT; ++o) {
            const float* wp = w + ((g * OCT + o) * IC + ic) * 9;
#pragma unroll
            for (int k = 0; k < 9; ++k) acc[o] = fmaf(wp[k], x[k], acc[o]);
        }
    }
#pragma unroll
    for (int o = 0; o < OCT; ++o) {
        float v = acc[o];
        if (RELU) v = fmaxf(v, 0.0f);
        out[(size_t)(b * OC + g * OCT + o) * POS + px] = v;
    }
}

// ---------------------------------------------------------------------------
// split-K 3x3 conv: SPLIT partial IC-range sums into part[].
// ---------------------------------------------------------------------------
template <int IC, int OC, int OCT, int IH, int IW, int STRIDE, int SPLIT>
__global__ __launch_bounds__(256) void convS_k(const float* __restrict__ in,
                                               const float* __restrict__ w,
                                               float* __restrict__ part) {
    constexpr int OH = (IH + 2 - 3) / STRIDE + 1;
    constexpr int OW = (IW + 2 - 3) / STRIDE + 1;
    constexpr int POS = OH * OW;
    constexpr int G = OC / OCT;
    constexpr int TOT = BATCH * G * POS;
    constexpr int ICS = IC / SPLIT;
    constexpr int N = BATCH * OC * POS;
    int idx = blockIdx.x * 256 + threadIdx.x;
    if (idx >= TOT * SPLIT) return;
    int s = idx / TOT, r = idx % TOT;
    int px = r % POS;
    int g = (r / POS) % G;
    int b = r / (POS * G);
    int ox = px % OW, oy = px / OW;
    int iy0 = oy * STRIDE - 1, ix0 = ox * STRIDE - 1;

    float acc[OCT];
#pragma unroll
    for (int o = 0; o < OCT; ++o) acc[o] = 0.0f;

    const float* ip = in + (size_t)b * IC * IH * IW;
    for (int ic = s * ICS; ic < (s + 1) * ICS; ++ic) {
        const float* ipc = ip + ic * IH * IW;
        float x[9];
#pragma unroll
        for (int ky = 0; ky < 3; ++ky) {
            int iy = iy0 + ky;
#pragma unroll
            for (int kx = 0; kx < 3; ++kx) {
                int ix = ix0 + kx;
                bool ok = (iy >= 0) && (iy < IH) && (ix >= 0) && (ix < IW);
                x[ky * 3 + kx] = ok ? ipc[iy * IW + ix] : 0.0f;
            }
        }
#pragma unroll
        for (int o = 0; o < OCT; ++o) {
            const float* wp = w + ((g * OCT + o) * IC + ic) * 9;
#pragma unroll
            for (int k = 0; k < 9; ++k) acc[o] = fmaf(wp[k], x[k], acc[o]);
        }
    }
#pragma unroll
    for (int o = 0; o < OCT; ++o)
        part[(size_t)s * N + (size_t)(b * OC + g * OCT + o) * POS + px] = acc[o];
}

// ---------------------------------------------------------------------------
// reduce split-K partials + bias + relu
// ---------------------------------------------------------------------------
template <int OC, int POS, int SPLIT, bool RELU, bool HASB>
__global__ __launch_bounds__(256) void reduce_k(const float* __restrict__ part,
                                                const float* __restrict__ bias,
                                                float* __restrict__ out) {
    constexpr int N = BATCH * OC * POS;
    int idx = blockIdx.x * 256 + threadIdx.x;
    if (idx >= N) return;
    int oc = (idx / POS) % OC;
    float a = HASB ? bias[oc] : 0.0f;
#pragma unroll
    for (int s = 0; s < SPLIT; ++s) a += part[(size_t)s * N + idx];
    out[idx] = RELU ? fmaxf(a, 0.0f) : a;
}

// ---------------------------------------------------------------------------
// fc1: folds cw1's split-16 reduce (+cb1+relu) into xin, then
// h1[b,r] = relu(fw1[r,:] . xin + fb1[r]).  512 blocks, 1 row per wave.
// ---------------------------------------------------------------------------
__global__ __launch_bounds__(256) void fc1_k(const float* __restrict__ part_cw1,
                                             const float* __restrict__ cb1,
                                             const float* __restrict__ fw1,
                                             const float* __restrict__ fb1,
                                             float* __restrict__ h1) {
    __shared__ float xin[1024];
    int t = threadIdx.x;
    int b = blockIdx.x >> 6;          // 64 blocks per batch
    int rgrp = blockIdx.x & 63;
    int wave = t >> 6, lane = t & 63;

    for (int i = t; i < 1024; i += 256) {
        float v = cb1[i >> 4];        // xg1 flat idx i = oc*16+px, POS=16
#pragma unroll
        for (int s = 0; s < 16; ++s) v += part_cw1[s * 8192 + b * 1024 + i];
        xin[i] = fmaxf(v, 0.0f);
    }
    __syncthreads();

    int r = (rgrp << 2) | wave;       // 0..255
    const float4* w4 = (const float4*)(fw1 + r * 1024);
    const float4* x4 = (const float4*)xin;
    float acc = 0.0f;
#pragma unroll
    for (int jj = 0; jj < 4; ++jj) {
        float4 wv = w4[lane + 64 * jj];
        float4 xv = x4[lane + 64 * jj];
        acc = fmaf(wv.x, xv.x, acc);
        acc = fmaf(wv.y, xv.y, acc);
        acc = fmaf(wv.z, xv.z, acc);
        acc = fmaf(wv.w, xv.w, acc);
    }
#pragma unroll
    for (int m = 32; m; m >>= 1) acc += __shfl_xor(acc, m, 64);
    if (lane == 0) h1[b * 256 + r] = fmaxf(acc + fb1[r], 0.0f);
}

// ---------------------------------------------------------------------------
// fc2: h2[b,r] = relu(fw2[r,:] . h1[b,:] + fb2[r]).  256 blocks.
// ---------------------------------------------------------------------------
__global__ __launch_bounds__(256) void fc2_k(const float* __restrict__ h1,
                                             const float* __restrict__ fw2,
                                             const float* __restrict__ fb2,
                                             float* __restrict__ h2) {
    int t = threadIdx.x;
    int b = blockIdx.x >> 5;
    int rgrp = blockIdx.x & 31;
    int wave = t >> 6, lane = t & 63;
    int r = (rgrp << 2) | wave;       // 0..127
    float4 wv = ((const float4*)(fw2 + r * 256))[lane];
    float4 xv = ((const float4*)(h1 + b * 256))[lane];
    float acc = fmaf(wv.x, xv.x, fmaf(wv.y, xv.y, fmaf(wv.z, xv.z, wv.w * xv.w)));
#pragma unroll
    for (int m = 32; m; m >>= 1) acc += __shfl_xor(acc, m, 64);
    if (lane == 0) h2[b * 128 + r] = fmaxf(acc + fb2[r], 0.0f);
}

// ---------------------------------------------------------------------------
// fc3: xgv[b,r] = fw3[r,:] . h2[b,:] + fb3[r].  128 blocks.
// ---------------------------------------------------------------------------
__global__ __launch_bounds__(256) void fc3_k(const float* __restrict__ h2,
                                             const float* __restrict__ fw3,
                                             const float* __restrict__ fb3,
                                             float* __restrict__ xgv) {
    int t = threadIdx.x;
    int b = blockIdx.x >> 4;
    int rgrp = blockIdx.x & 15;
    int wave = t >> 6, lane = t & 63;
    int r = (rgrp << 2) | wave;       // 0..63
    float2 wv = ((const float2*)(fw3 + r * 128))[lane];
    float2 xv = ((const float2*)(h2 + b * 128))[lane];
    float acc = fmaf(wv.x, xv.x, wv.y * xv.y);
#pragma unroll
    for (int m = 32; m; m >>= 1) acc += __shfl_xor(acc, m, 64);
    if (lane == 0) xgv[b * 64 + r] = acc + fb3[r];
}

// ---------------------------------------------------------------------------
// fuse: folds lw2's split-8 reduce (no bias/relu). One block per (b,d).
// bg[b,d,px] = fub[d] + sum_c fuw[d,c] * relu(xg[b,c] + xl2[b,c,px])
// ---------------------------------------------------------------------------
__global__ __launch_bounds__(256) void fuse_k(const float* __restrict__ xg,
                                              const float* __restrict__ part_lw2,
                                              const float* __restrict__ fuw,
                                              const float* __restrict__ fub,
                                              float* __restrict__ bg) {
    int px = threadIdx.x;             // 0..255
    int d = blockIdx.x & 7;
    int b = blockIdx.x >> 3;
    float acc = fub[d];
    for (int c = 0; c < 64; ++c) {
        int base = (b * 64 + c) * 256 + px;
        float xlv = 0.0f;
#pragma unroll
        for (int s = 0; s < 8; ++s) xlv += part_lw2[s * 131072 + base];
        float f = fmaxf(xg[b * 64 + c] + xlv, 0.0f);
        acc = fmaf(fuw[d * 64 + c], f, acc);
    }
    bg[(b * 8 + d) * 256 + px] = acc;
}

// ---------------------------------------------------------------------------
// guide+slice (unchanged): vertical-first separable blur, sliding register
// windows, per-px guide MLP + trilinear grid slice.
// ---------------------------------------------------------------------------
__global__ __launch_bounds__(256) void guide_slice_k(const float* __restrict__ lqs,
                                                     const float* __restrict__ bgp,
                                                     const float* __restrict__ gw1,
                                                     const float* __restrict__ gb1,
                                                     const float* __restrict__ gw2,
                                                     const float* __restrict__ gb2,
                                                     float* __restrict__ out) {
    constexpr int TW = 64, TH = 32;
    __shared__ float sBH[3][TH][81];
    __shared__ float sBG[2048];
    __shared__ float sW1[48], sB1[16], sW2[16], sB2v[1];

    int t = threadIdx.x;
    int bx = blockIdx.x & 15;
    int by = (blockIdx.x >> 4) & 31;
    int b = blockIdx.x >> 9;
    int x0 = bx * TW, y0 = by * TH;

    float gv[17];
    {
        float gs = 0.0f;
#pragma unroll
        for (int i = 0; i < 17; ++i) {
            float d = (float)i - 8.0f;
            gv[i] = expf(-(d * d) * 0.125f);
            gs += gv[i];
        }
        float inv = 1.0f / gs;
#pragma unroll
        for (int i = 0; i < 17; ++i) gv[i] *= inv;
    }

    for (int i = t; i < 2048; i += 256) sBG[i] = bgp[b * 2048 + i];
    if (t < 48) sW1[t] = gw1[t];
    if (t < 16) { sB1[t] = gb1[t]; sW2[t] = gw2[t]; }
    if (t == 0) sB2v[0] = gb2[0];

    if (t < 240) {
        int c = t / 80, xo = t % 80;
        int gx = reflect1024(x0 + xo - 8);
        const float* colp = lqs + (size_t)(b * 3 + c) * HH * WW + gx;
        float win[17];
#pragma unroll
        for (int i = 0; i < 16; ++i)
            win[i] = colp[(size_t)reflect1024(y0 - 8 + i) * WW];
#pragma unroll
        for (int j = 0; j < TH; ++j) {
            win[(16 + j) % 17] = colp[(size_t)reflect1024(y0 + 8 + j) * WW];
            float acc = 0.0f;
#pragma unroll
            for (int i = 0; i < 17; ++i) acc = fmaf(gv[i], win[(j + i) % 17], acc);
            sBH[c][j][xo] = acc;
        }
    }
    __syncthreads();

    int yy = t >> 3, xs = (t & 7) * 8;
    int Y = y0 + yy;
    float fy = fminf(fmaxf((Y + 0.5f) * (1.0f / 64.0f) + 3.5f, 0.0f), 15.0f);
    float yf = floorf(fy);
    int yi = (int)yf;
    float ay = fy - yf;
    int yi1 = min(yi + 1, 15);

    float bcv[3][8];
#pragma unroll
    for (int c = 0; c < 3; ++c) {
        float win[17];
#pragma unroll
        for (int i = 0; i < 16; ++i) win[i] = sBH[c][yy][xs + i];
#pragma unroll
        for (int j = 0; j < 8; ++j) {
            win[(16 + j) % 17] = sBH[c][yy][xs + 16 + j];
            float acc = 0.0f;
#pragma unroll
            for (int i = 0; i < 17; ++i) acc = fmaf(gv[i], win[(j + i) % 17], acc);
            bcv[c][j] = acc;
        }
    }

    float val[8];
#pragma unroll
    for (int j = 0; j < 8; ++j) {
        float b0 = bcv[0][j], b1 = bcv[1][j], b2 = bcv[2][j];
        float s = sB2v[0];
#pragma unroll
        for (int c = 0; c < 16; ++c) {
            float g1 = fmaf(sW1[c * 3 + 0], b0,
                       fmaf(sW1[c * 3 + 1], b1,
                       fmaf(sW1[c * 3 + 2], b2, sB1[c])));
            s = fmaf(sW2[c], fmaxf(g1, 0.0f), s);
        }
        float sig = 1.0f / (1.0f + expf(-s));
        float guide = sig * 2.0f - 0.5f;

        int X = x0 + xs + j;
        float fx = fminf(fmaxf((X + 0.5f) * (1.0f / 64.0f) + 3.5f, 0.0f), 15.0f);
        float fz = fminf(fmaxf(fmaf(guide, 4.0f, 3.5f), 0.0f), 7.0f);
        float xf = floorf(fx), zf = floorf(fz);
        int xi = (int)xf, zi = (int)zf;
        float ax = fx - xf, az = fz - zf;
        int xi1 = min(xi + 1, 15), zi1 = min(zi + 1, 7);

        const float* g0 = sBG + zi * 256;
        const float* g1p = sBG + zi1 * 256;
        int i00 = yi * 16 + xi, i01 = yi * 16 + xi1;
        int i10 = yi1 * 16 + xi, i11 = yi1 * 16 + xi1;
        float c00 = g0[i00] + az * (g1p[i00] - g0[i00]);
        float c01 = g0[i01] + az * (g1p[i01] - g0[i01]);
        float c10 = g0[i10] + az * (g1p[i10] - g0[i10]);
        float c11 = g0[i11] + az * (g1p[i11] - g0[i11]);
        float c0 = c00 + ay * (c10 - c00);
        float c1 = c01 + ay * (c11 - c01);
        val[j] = c0 + ax * (c1 - c0);
    }
    float4* op = (float4*)(out + (size_t)b * HH * WW + (size_t)Y * WW + x0 + xs);
    op[0] = make_float4(val[0], val[1], val[2], val[3]);
    op[1] = make_float4(val[4], val[5], val[6], val[7]);
}

// ---------------------------------------------------------------------------
extern "C" void kernel_launch(void* const* d_in, const int* in_sizes, int n_in,
                              void* d_out, int out_size, void* d_ws, size_t ws_size,
                              hipStream_t stream) {
    const float* lqs = (const float*)d_in[0];
    const float* evs = (const float*)d_in[1];
    const float* gw1 = (const float*)d_in[2];
    const float* gb1 = (const float*)d_in[3];
    const float* gw2 = (const float*)d_in[4];
    const float* gb2 = (const float*)d_in[5];
    const float* sw0 = (const float*)d_in[6];
    const float* sb0 = (const float*)d_in[7];
    const float* sw1 = (const float*)d_in[8];
    const float* sb1 = (const float*)d_in[9];
    const float* sw2 = (const float*)d_in[10];
    const float* sb2 = (const float*)d_in[11];
    const float* sw3 = (const float*)d_in[12];
    const float* sb3 = (const float*)d_in[13];
    const float* cw0 = (const float*)d_in[14];
    const float* cb0 = (const float*)d_in[15];
    const float* cw1 = (const float*)d_in[16];
    const float* cb1 = (const float*)d_in[17];
    const float* fw1 = (const float*)d_in[18];
    const float* fb1 = (const float*)d_in[19];
    const float* fw2 = (const float*)d_in[20];
    const float* fb2 = (const float*)d_in[21];
    const float* fw3 = (const float*)d_in[22];
    const float* fb3 = (const float*)d_in[23];
    const float* lw1 = (const float*)d_in[24];
    const float* lb1 = (const float*)d_in[25];
    const float* lw2 = (const float*)d_in[26];
    const float* fuw = (const float*)d_in[27];
    const float* fub = (const float*)d_in[28];
    float* out = (float*)d_out;

    float* ws = (float*)d_ws;
    float* o0 = ws;                  // [8,8,128,128]   1048576
    float* o1 = o0 + 1048576;        // [8,16,64,64]     524288
    float* o2 = o1 + 524288;         // [8,32,32,32]     262144
    float* o3 = o2 + 262144;         // [8,64,16,16]     131072
    float* xl1 = o3 + 131072;        // [8,64,16,16]     131072
    float* xg0 = xl1 + 131072;       // [8,64,8,8]        32768
    float* xgv = xg0 + 32768;        // [8,64]              512
    float* bg = xgv + 512;           // [8,8,16,16]       16384
    float* h1 = bg + 16384;          // [8,256]            2048
    float* h2 = h1 + 2048;           // [8,128]            1024
    float* partA = h2 + 1024;        // reused partials   1048576
    float* part_lw2 = partA + 1048576;  // persists       1048576
    float* part_cw1 = part_lw2 + 1048576;  // persists     131072
    // total ~4.4M floats = 17.5 MB

    conv0_k<<<128, 256, 0, stream>>>(lqs, evs, sw0, sb0, o0);
    convN_k<8, 16, 8, 128, 128, 2, true, true><<<256, 256, 0, stream>>>(o0, sw1, sb1, o1);
    // conv2: 16->32 @64x64, split 4  (131072 threads)
    convS_k<16, 32, 8, 64, 64, 2, 4><<<512, 256, 0, stream>>>(o1, sw2, partA);
    reduce_k<32, 1024, 4, true, true><<<1024, 256, 0, stream>>>(partA, sb2, o2);
    // conv3: 32->64 @32x32, split 8  (131072 threads)
    convS_k<32, 64, 8, 32, 32, 2, 8><<<512, 256, 0, stream>>>(o2, sw3, partA);
    reduce_k<64, 256, 8, true, true><<<512, 256, 0, stream>>>(partA, sb3, o3);
    // local path: split 8
    convS_k<64, 64, 8, 16, 16, 1, 8><<<512, 256, 0, stream>>>(o3, lw1, partA);
    reduce_k<64, 256, 8, true, true><<<512, 256, 0, stream>>>(partA, lb1, xl1);
    convS_k<64, 64, 8, 16, 16, 1, 8><<<512, 256, 0, stream>>>(xl1, lw2, part_lw2);
    // (lw2 reduce folded into fuse_k)
    // global path: split 16
    convS_k<64, 64, 8, 16, 16, 2, 16><<<256, 256, 0, stream>>>(o3, cw0, partA);
    reduce_k<64, 64, 16, true, true><<<128, 256, 0, stream>>>(partA, cb0, xg0);
    convS_k<64, 64, 4, 8, 8, 2, 16><<<128, 256, 0, stream>>>(xg0, cw1, part_cw1);
    // (cw1 reduce folded into fc1_k)
    fc1_k<<<512, 256, 0, stream>>>(part_cw1, cb1, fw1, fb1, h1);
    fc2_k<<<256, 256, 0, stream>>>(h1, fw2, fb2, h2);
    fc3_k<<<128, 256, 0, stream>>>(h2, fw3, fb3, xgv);
    fuse_k<<<64, 256, 0, stream>>>(xgv, part_lw2, fuw, fub, bg);
    guide_slice_k<<<BATCH * 32 * 16, 256, 0, stream>>>(lqs, bg, gw1, gb1, gw2, gb2, out);
}